// Round 1
// baseline (892.712 us; speedup 1.0000x reference)
//
#include <hip/hip_runtime.h>
#include <math.h>

// ---------------------------------------------------------------------------
// GAT 3-layer pipeline, fp32 baseline.
// Key restructurings vs reference:
//   el = h_src @ wl.T where wl[h,:] = al[h,:] @ Wsrc_h  (never build fs for el)
//   agg = (sum_e (ex_e/s) * h_src[src_e,:]) @ Wsrc_h.T  (aggregate BEFORE GEMM)
// Per layer: build wl/wr -> el/er -> CSR(count,scan,scatter) -> edge max (atomicMax
// on order-encoded uint) -> edge exp + scatter + denom -> per-dst gather z -> per-head
// GEMM (+bias+ELU). Final: head-mean + log_softmax.
// ---------------------------------------------------------------------------

static const int L_NS[3]   = {150000, 25000, 6000};
static const int L_ND[3]   = {25000, 6000, 1024};
static const int L_E[3]    = {375000, 90000, 10240};
static const int L_FIN[3]  = {256, 512, 512};
static const int L_FOUT[3] = {128, 128, 47};

__device__ __forceinline__ unsigned fenc(float f) {
  unsigned u = __float_as_uint(f);
  return (u & 0x80000000u) ? ~u : (u | 0x80000000u);
}
__device__ __forceinline__ float fdec(unsigned u) {
  return (u & 0x80000000u) ? __uint_as_float(u & 0x7fffffffu) : __uint_as_float(~u);
}
__device__ __forceinline__ float lrelu(float v) { return v >= 0.f ? v : 0.2f * v; }

// wlr[0..4*Fin) = wl (al . Wsrc), wlr[4*Fin..8*Fin) = wr (ar . Wdst)
__global__ void k_build_wlr(const float* __restrict__ Wsrc, const float* __restrict__ Wdst,
                            const float* __restrict__ al, const float* __restrict__ ar,
                            float* __restrict__ wlr, int Fin, int Fout) {
  int idx = blockIdx.x * 256 + threadIdx.x;
  if (idx >= 8 * Fin) return;
  int which = idx / (4 * Fin);
  int rem = idx - which * 4 * Fin;
  int h = rem / Fin, k = rem - h * Fin;
  const float* W = which ? Wdst : Wsrc;
  const float* a = which ? ar : al;
  float acc = 0.f;
  for (int d = 0; d < Fout; ++d)
    acc += a[h * Fout + d] * W[(size_t)(h * Fout + d) * Fin + k];
  wlr[idx] = acc;
}

// one wave per node: ell[n,h] = dot(Hs[n,:], wl[h,:]); err[n,h] for n < Nd
__global__ __launch_bounds__(256) void k_dot_lr(
    const float* __restrict__ Hs, const float* __restrict__ wlr,
    float* __restrict__ ell, float* __restrict__ err, int Ns, int Nd, int Fin) {
  int node = blockIdx.x * 4 + (threadIdx.x >> 6);
  int lane = threadIdx.x & 63;
  if (node >= Ns) return;
  bool nR = node < Nd;
  float a[4] = {0.f, 0.f, 0.f, 0.f}, b[4] = {0.f, 0.f, 0.f, 0.f};
  const float* xr = Hs + (size_t)node * Fin;
  for (int k = lane * 4; k < Fin; k += 256) {
    float4 xv = *reinterpret_cast<const float4*>(xr + k);
#pragma unroll
    for (int h = 0; h < 4; ++h) {
      float4 wv = *reinterpret_cast<const float4*>(wlr + h * Fin + k);
      a[h] += xv.x * wv.x + xv.y * wv.y + xv.z * wv.z + xv.w * wv.w;
    }
    if (nR) {
#pragma unroll
      for (int h = 0; h < 4; ++h) {
        float4 wv = *reinterpret_cast<const float4*>(wlr + (4 + h) * Fin + k);
        b[h] += xv.x * wv.x + xv.y * wv.y + xv.z * wv.z + xv.w * wv.w;
      }
    }
  }
#pragma unroll
  for (int h = 0; h < 4; ++h) {
    for (int off = 32; off > 0; off >>= 1) {
      a[h] += __shfl_xor(a[h], off);
      b[h] += __shfl_xor(b[h], off);
    }
  }
  if (lane == 0) {
#pragma unroll
    for (int h = 0; h < 4; ++h) ell[(size_t)node * 4 + h] = a[h];
    if (nR) {
#pragma unroll
      for (int h = 0; h < 4; ++h) err[(size_t)node * 4 + h] = b[h];
    }
  }
}

__global__ void k_count(const int* __restrict__ dst, int* __restrict__ cnt, int E) {
  int e = blockIdx.x * 256 + threadIdx.x;
  if (e < E) atomicAdd(&cnt[dst[e]], 1);
}

// single-block exclusive scan; rowptr[0..Nd], cursor[i]=rowptr[i]
__global__ __launch_bounds__(1024) void k_scan(const int* __restrict__ cnt,
                                               int* __restrict__ rowptr,
                                               int* __restrict__ cursor, int Nd) {
  __shared__ int sm[1024];
  __shared__ int carry;
  int t = threadIdx.x;
  if (t == 0) { carry = 0; rowptr[0] = 0; }
  __syncthreads();
  for (int base = 0; base < Nd; base += 1024) {
    int i = base + t;
    int v = (i < Nd) ? cnt[i] : 0;
    sm[t] = v;
    __syncthreads();
    for (int off = 1; off < 1024; off <<= 1) {
      int u = (t >= off) ? sm[t - off] : 0;
      __syncthreads();
      sm[t] += u;
      __syncthreads();
    }
    int inc = sm[t] + carry;
    if (i < Nd) { rowptr[i + 1] = inc; cursor[i] = inc - v; }
    __syncthreads();
    if (t == 1023) carry = inc;
    __syncthreads();
  }
}

__global__ void k_fill_u32(unsigned* __restrict__ p, unsigned v, int n) {
  int i = blockIdx.x * 256 + threadIdx.x;
  if (i < n) p[i] = v;
}

__global__ void k_edge_max(const int* __restrict__ src, const int* __restrict__ dst,
                           const float* __restrict__ ell, const float* __restrict__ err,
                           unsigned* __restrict__ menc, int E) {
  int e = blockIdx.x * 256 + threadIdx.x;
  if (e >= E) return;
  int s = src[e], d = dst[e];
  float4 el4 = *reinterpret_cast<const float4*>(ell + (size_t)s * 4);
  float4 er4 = *reinterpret_cast<const float4*>(err + (size_t)d * 4);
  unsigned* mb = menc + (size_t)d * 4;
  atomicMax(mb + 0, fenc(lrelu(el4.x + er4.x)));
  atomicMax(mb + 1, fenc(lrelu(el4.y + er4.y)));
  atomicMax(mb + 2, fenc(lrelu(el4.z + er4.z)));
  atomicMax(mb + 3, fenc(lrelu(el4.w + er4.w)));
}

// ex = exp(e - m), scatter into CSR slot order, accumulate denom s
__global__ void k_edge_exp(const int* __restrict__ src, const int* __restrict__ dst,
                           const float* __restrict__ ell, const float* __restrict__ err,
                           const unsigned* __restrict__ menc, float* __restrict__ sbuf,
                           int* __restrict__ cursor, int* __restrict__ colv,
                           float* __restrict__ exs, int E) {
  int e = blockIdx.x * 256 + threadIdx.x;
  if (e >= E) return;
  int s = src[e], d = dst[e];
  int slot = atomicAdd(&cursor[d], 1);
  colv[slot] = s;
  float4 el4 = *reinterpret_cast<const float4*>(ell + (size_t)s * 4);
  float4 er4 = *reinterpret_cast<const float4*>(err + (size_t)d * 4);
  const unsigned* mb = menc + (size_t)d * 4;
  float w0 = __expf(lrelu(el4.x + er4.x) - fdec(mb[0]));
  float w1 = __expf(lrelu(el4.y + er4.y) - fdec(mb[1]));
  float w2 = __expf(lrelu(el4.z + er4.z) - fdec(mb[2]));
  float w3 = __expf(lrelu(el4.w + er4.w) - fdec(mb[3]));
  *reinterpret_cast<float4*>(exs + (size_t)slot * 4) = make_float4(w0, w1, w2, w3);
  float* sb = sbuf + (size_t)d * 4;
  atomicAdd(sb + 0, w0);
  atomicAdd(sb + 1, w1);
  atomicAdd(sb + 2, w2);
  atomicAdd(sb + 3, w3);
}

// per-dst weighted feature gather: Z[n,h,:] = (1/s[n,h]) * sum_e ex_e * Hs[src_e,:]
template <int FIN>
__global__ __launch_bounds__(256) void k_gather(
    const float* __restrict__ Hs, const int* __restrict__ rowptr,
    const int* __restrict__ colv, const float* __restrict__ exs,
    const float* __restrict__ sbuf, float* __restrict__ Z) {
  int n = blockIdx.x, t = threadIdx.x;
  int beg = rowptr[n], end = rowptr[n + 1];
  float inv0 = 1.f / fmaxf(sbuf[(size_t)n * 4 + 0], 1e-9f);
  float inv1 = 1.f / fmaxf(sbuf[(size_t)n * 4 + 1], 1e-9f);
  float inv2 = 1.f / fmaxf(sbuf[(size_t)n * 4 + 2], 1e-9f);
  float inv3 = 1.f / fmaxf(sbuf[(size_t)n * 4 + 3], 1e-9f);
  float a00 = 0.f, a10 = 0.f, a20 = 0.f, a30 = 0.f;
  float a01 = 0.f, a11 = 0.f, a21 = 0.f, a31 = 0.f;
  __shared__ float wsm[256];
  __shared__ int csm[64];
  for (int c0 = beg; c0 < end; c0 += 64) {
    int cnt = min(64, end - c0);
    __syncthreads();
    if (t < cnt) csm[t] = colv[c0 + t];
    if (t < cnt * 4) wsm[t] = exs[(size_t)c0 * 4 + t];
    __syncthreads();
    for (int j = 0; j < cnt; ++j) {
      const float* xp = Hs + (size_t)csm[j] * FIN + t;
      float x0 = xp[0];
      float w0 = wsm[j * 4 + 0], w1 = wsm[j * 4 + 1], w2 = wsm[j * 4 + 2], w3 = wsm[j * 4 + 3];
      a00 = fmaf(w0, x0, a00); a10 = fmaf(w1, x0, a10);
      a20 = fmaf(w2, x0, a20); a30 = fmaf(w3, x0, a30);
      if (FIN == 512) {
        float x1 = xp[256];
        a01 = fmaf(w0, x1, a01); a11 = fmaf(w1, x1, a11);
        a21 = fmaf(w2, x1, a21); a31 = fmaf(w3, x1, a31);
      }
    }
  }
  float* zb = Z + (size_t)n * 4 * FIN + t;
  zb[0 * FIN] = a00 * inv0; zb[1 * FIN] = a10 * inv1;
  zb[2 * FIN] = a20 * inv2; zb[3 * FIN] = a30 * inv3;
  if (FIN == 512) {
    zb[0 * FIN + 256] = a01 * inv0; zb[1 * FIN + 256] = a11 * inv1;
    zb[2 * FIN + 256] = a21 * inv2; zb[3 * FIN + 256] = a31 * inv3;
  }
}

// per-head GEMM: out[m, h*N+n] = (Z_h @ W_h^T)[m,n] + bias[h*N+n]  (opt ELU)
// A row-major lda=ldz (=4*K), B row-major ldb=K. 64x64 tile, 256 thr, 4x4 micro.
template <bool ACT>
__global__ __launch_bounds__(256) void k_gemm(
    const float* __restrict__ Zb, const float* __restrict__ W,
    const float* __restrict__ bias, float* __restrict__ out,
    int M, int N, int K, int ldz, int ldo) {
  int h = blockIdx.z;
  const float* A = Zb + (size_t)h * K;
  const float* B = W + (size_t)h * N * K;
  __shared__ __align__(16) float As[16][68];  // [k][m], padded
  __shared__ __align__(16) float Bs[16][68];  // [k][n], padded
  int tid = threadIdx.x;
  int tx = tid & 15, ty = tid >> 4;
  int bm = blockIdx.x * 64, bn = blockIdx.y * 64;
  int lr = tid >> 2;          // 0..63
  int lc = (tid & 3) * 4;     // 0,4,8,12
  float acc[4][4] = {};
  int gm = bm + lr, gn = bn + lr;
  const float* Ap = (gm < M) ? (A + (size_t)gm * ldz + lc) : nullptr;
  const float* Bp = (gn < N) ? (B + (size_t)gn * K + lc) : nullptr;
  for (int k0 = 0; k0 < K; k0 += 16) {
    float4 va = make_float4(0.f, 0.f, 0.f, 0.f);
    float4 vb = make_float4(0.f, 0.f, 0.f, 0.f);
    if (Ap) va = *reinterpret_cast<const float4*>(Ap + k0);
    if (Bp) vb = *reinterpret_cast<const float4*>(Bp + k0);
    __syncthreads();  // prev iter's readers done before overwrite
    As[lc + 0][lr] = va.x; As[lc + 1][lr] = va.y; As[lc + 2][lr] = va.z; As[lc + 3][lr] = va.w;
    Bs[lc + 0][lr] = vb.x; Bs[lc + 1][lr] = vb.y; Bs[lc + 2][lr] = vb.z; Bs[lc + 3][lr] = vb.w;
    __syncthreads();
#pragma unroll
    for (int kk = 0; kk < 16; ++kk) {
      float4 a4 = *reinterpret_cast<const float4*>(&As[kk][ty * 4]);
      float4 b4 = *reinterpret_cast<const float4*>(&Bs[kk][tx * 4]);
      float av[4] = {a4.x, a4.y, a4.z, a4.w};
      float bv[4] = {b4.x, b4.y, b4.z, b4.w};
#pragma unroll
      for (int i = 0; i < 4; ++i)
#pragma unroll
        for (int j = 0; j < 4; ++j)
          acc[i][j] = fmaf(av[i], bv[j], acc[i][j]);
    }
  }
#pragma unroll
  for (int i = 0; i < 4; ++i) {
    int om = bm + ty * 4 + i;
    if (om >= M) continue;
#pragma unroll
    for (int j = 0; j < 4; ++j) {
      int on = bn + tx * 4 + j;
      if (on >= N) continue;
      float v = acc[i][j] + bias[h * N + on];
      if (ACT) v = v > 0.f ? v : expm1f(v);
      out[(size_t)om * ldo + h * N + on] = v;
    }
  }
}

// mean over 4 heads (C=47) + log_softmax; one wave per node
__global__ __launch_bounds__(256) void k_mean_lsm(const float* __restrict__ rst2,
                                                  float* __restrict__ out, int Nd) {
  int node = blockIdx.x * 4 + (threadIdx.x >> 6);
  int lane = threadIdx.x & 63;
  if (node >= Nd) return;
  const float* r = rst2 + (size_t)node * 188;
  float vv = 0.f;
  if (lane < 47)
    vv = 0.25f * (r[lane] + r[47 + lane] + r[94 + lane] + r[141 + lane]);
  float m = (lane < 47) ? vv : -INFINITY;
  for (int off = 32; off > 0; off >>= 1) m = fmaxf(m, __shfl_xor(m, off));
  float ex = (lane < 47) ? __expf(vv - m) : 0.f;
  float ss = ex;
  for (int off = 32; off > 0; off >>= 1) ss += __shfl_xor(ss, off);
  if (lane < 47) out[(size_t)node * 47 + lane] = vv - m - logf(ss);
}

extern "C" void kernel_launch(void* const* d_in, const int* in_sizes, int n_in,
                              void* d_out, int out_size, void* d_ws, size_t ws_size,
                              hipStream_t stream) {
  (void)in_sizes; (void)n_in; (void)out_size; (void)ws_size;
  const float* x = (const float*)d_in[0];
  const int* srcs[3] = {(const int*)d_in[1], (const int*)d_in[3], (const int*)d_in[5]};
  const int* dsts[3] = {(const int*)d_in[2], (const int*)d_in[4], (const int*)d_in[6]};
  const float* Wsrc[3] = {(const float*)d_in[7], (const float*)d_in[12], (const float*)d_in[17]};
  const float* Wdst[3] = {(const float*)d_in[8], (const float*)d_in[13], (const float*)d_in[18]};
  const float* al[3]   = {(const float*)d_in[9], (const float*)d_in[14], (const float*)d_in[19]};
  const float* ar[3]   = {(const float*)d_in[10], (const float*)d_in[15], (const float*)d_in[20]};
  const float* bb[3]   = {(const float*)d_in[11], (const float*)d_in[16], (const float*)d_in[21]};

  char* p = (char*)d_ws;
  auto alloc = [&](size_t bytes) -> void* {
    void* r = (void*)p;
    p += (bytes + 255) & ~(size_t)255;
    return r;
  };
  // ~178 MB total
  float* z      = (float*)alloc((size_t)25000 * 4 * 256 * 4);   // max z: L0 (102.4MB)
  float* h1     = (float*)alloc((size_t)25000 * 512 * 4);
  float* h2     = (float*)alloc((size_t)6000 * 512 * 4);
  float* rst2   = (float*)alloc((size_t)1024 * 188 * 4);
  float* ell    = (float*)alloc((size_t)150000 * 4 * 4);
  float* err    = (float*)alloc((size_t)25000 * 4 * 4);
  unsigned* menc= (unsigned*)alloc((size_t)25000 * 4 * 4);
  float* sbuf   = (float*)alloc((size_t)25000 * 4 * 4);
  float* exs    = (float*)alloc((size_t)375000 * 4 * 4);
  int* cnt      = (int*)alloc((size_t)25000 * 4);
  int* rowptr   = (int*)alloc((size_t)25001 * 4);
  int* cursor   = (int*)alloc((size_t)25000 * 4);
  int* colv     = (int*)alloc((size_t)375000 * 4);
  float* wlr    = (float*)alloc((size_t)8 * 512 * 4);

  const float* Hs = x;
  float* outs[3] = {h1, h2, rst2};

  for (int l = 0; l < 3; ++l) {
    int Ns = L_NS[l], Nd = L_ND[l], E = L_E[l], Fin = L_FIN[l], Fout = L_FOUT[l];
    k_build_wlr<<<(8 * Fin + 255) / 256, 256, 0, stream>>>(Wsrc[l], Wdst[l], al[l], ar[l], wlr, Fin, Fout);
    k_dot_lr<<<(Ns + 3) / 4, 256, 0, stream>>>(Hs, wlr, ell, err, Ns, Nd, Fin);
    hipMemsetAsync(cnt, 0, (size_t)Nd * sizeof(int), stream);
    k_count<<<(E + 255) / 256, 256, 0, stream>>>(dsts[l], cnt, E);
    k_scan<<<1, 1024, 0, stream>>>(cnt, rowptr, cursor, Nd);
    k_fill_u32<<<(Nd * 4 + 255) / 256, 256, 0, stream>>>(menc, 0x007FFFFFu /* enc(-inf) */, Nd * 4);
    k_edge_max<<<(E + 255) / 256, 256, 0, stream>>>(srcs[l], dsts[l], ell, err, menc, E);
    hipMemsetAsync(sbuf, 0, (size_t)Nd * 4 * sizeof(float), stream);
    k_edge_exp<<<(E + 255) / 256, 256, 0, stream>>>(srcs[l], dsts[l], ell, err, menc, sbuf, cursor, colv, exs, E);
    if (Fin == 256)
      k_gather<256><<<Nd, 256, 0, stream>>>(Hs, rowptr, colv, exs, sbuf, z);
    else
      k_gather<512><<<Nd, 256, 0, stream>>>(Hs, rowptr, colv, exs, sbuf, z);
    dim3 g((Nd + 63) / 64, (Fout + 63) / 64, 4);
    if (l < 2)
      k_gemm<true><<<g, 256, 0, stream>>>(z, Wsrc[l], bb[l], outs[l], Nd, Fout, Fin, 4 * Fin, 4 * Fout);
    else
      k_gemm<false><<<g, 256, 0, stream>>>(z, Wsrc[l], bb[l], outs[l], Nd, Fout, Fin, 4 * Fin, 4 * Fout);
    Hs = outs[l];
  }
  k_mean_lsm<<<(1024 + 3) / 4, 256, 0, stream>>>(rst2, (float*)d_out, 1024);
}

// Round 2
// 711.767 us; speedup vs baseline: 1.2542x; 1.2542x over previous
//
#include <hip/hip_runtime.h>
#include <math.h>

// ---------------------------------------------------------------------------
// GAT 3-layer pipeline. bf16 features + MFMA GEMMs, fp32 edge softmax.
//   el = h @ wl.T, wl[h,:] = al[h,:] @ Wsrc_h   (no fs materialization)
//   agg = (softmax-weighted sum of raw feats) @ Wsrc_h.T  (aggregate first)
// ---------------------------------------------------------------------------

static const int L_NS[3]   = {150000, 25000, 6000};
static const int L_ND[3]   = {25000, 6000, 1024};
static const int L_E[3]    = {375000, 90000, 10240};
static const int L_FIN[3]  = {256, 512, 512};
static const int L_FOUT[3] = {128, 128, 47};

typedef short bf8_t __attribute__((ext_vector_type(8)));
typedef float f32x4 __attribute__((ext_vector_type(4)));

__device__ __forceinline__ unsigned fenc(float f) {
  unsigned u = __float_as_uint(f);
  return (u & 0x80000000u) ? ~u : (u | 0x80000000u);
}
__device__ __forceinline__ float fdec(unsigned u) {
  return (u & 0x80000000u) ? __uint_as_float(u & 0x7fffffffu) : __uint_as_float(~u);
}
__device__ __forceinline__ float lrelu(float v) { return v >= 0.f ? v : 0.2f * v; }
__device__ __forceinline__ unsigned short f2b(float f) {
  unsigned u = __float_as_uint(f);
  unsigned r = u + 0x7fffu + ((u >> 16) & 1u);
  return (unsigned short)(r >> 16);
}
__device__ __forceinline__ float b2f(unsigned v) {  // low 16 bits
  return __uint_as_float(v << 16);
}

// wlr[0..4*Fin) = wl (al . Wsrc), wlr[4*Fin..8*Fin) = wr (ar . Wdst)   (fp32)
__global__ void k_build_wlr(const float* __restrict__ Wsrc, const float* __restrict__ Wdst,
                            const float* __restrict__ al, const float* __restrict__ ar,
                            float* __restrict__ wlr, int Fin, int Fout) {
  int idx = blockIdx.x * 256 + threadIdx.x;
  if (idx >= 8 * Fin) return;
  int which = idx / (4 * Fin);
  int rem = idx - which * 4 * Fin;
  int h = rem / Fin, k = rem - h * Fin;
  const float* W = which ? Wdst : Wsrc;
  const float* a = which ? ar : al;
  float acc = 0.f;
  for (int d = 0; d < Fout; ++d)
    acc += a[h * Fout + d] * W[(size_t)(h * Fout + d) * Fin + k];
  wlr[idx] = acc;
}

__global__ void k_cvt_bf(const float* __restrict__ in, unsigned short* __restrict__ out, int n) {
  int i = blockIdx.x * 256 + threadIdx.x;
  if (i < n) out[i] = f2b(in[i]);
}

// layer 0: fp32 x -> ell/err + bf16 copy. Fin=256, one wave per node, lane covers k=lane*4.
__global__ __launch_bounds__(256) void k_dot_cvt(
    const float* __restrict__ x, const float* __restrict__ wlr,
    unsigned short* __restrict__ xbf, float* __restrict__ ell, float* __restrict__ err,
    int Ns, int Nd) {
  int node = blockIdx.x * 4 + (threadIdx.x >> 6);
  int lane = threadIdx.x & 63;
  if (node >= Ns) return;
  float4 xv = *reinterpret_cast<const float4*>(x + (size_t)node * 256 + lane * 4);
  ushort4 ub;
  ub.x = f2b(xv.x); ub.y = f2b(xv.y); ub.z = f2b(xv.z); ub.w = f2b(xv.w);
  *reinterpret_cast<ushort4*>(xbf + (size_t)node * 256 + lane * 4) = ub;
  bool nR = node < Nd;
  float a[4], b[4];
#pragma unroll
  for (int h = 0; h < 4; ++h) {
    float4 wv = *reinterpret_cast<const float4*>(wlr + h * 256 + lane * 4);
    a[h] = xv.x * wv.x + xv.y * wv.y + xv.z * wv.z + xv.w * wv.w;
    b[h] = 0.f;
    if (nR) {
      float4 w2 = *reinterpret_cast<const float4*>(wlr + 1024 + h * 256 + lane * 4);
      b[h] = xv.x * w2.x + xv.y * w2.y + xv.z * w2.z + xv.w * w2.w;
    }
  }
#pragma unroll
  for (int h = 0; h < 4; ++h) {
    for (int off = 32; off > 0; off >>= 1) {
      a[h] += __shfl_xor(a[h], off);
      b[h] += __shfl_xor(b[h], off);
    }
  }
  if (lane == 0) {
#pragma unroll
    for (int h = 0; h < 4; ++h) ell[(size_t)node * 4 + h] = a[h];
    if (nR) {
#pragma unroll
      for (int h = 0; h < 4; ++h) err[(size_t)node * 4 + h] = b[h];
    }
  }
}

// layers 1/2: bf16 features, Fin=512, one wave per node, lane covers k=lane*8.
__global__ __launch_bounds__(256) void k_dot_bf(
    const unsigned short* __restrict__ Hs, const float* __restrict__ wlr,
    float* __restrict__ ell, float* __restrict__ err, int Ns, int Nd) {
  int node = blockIdx.x * 4 + (threadIdx.x >> 6);
  int lane = threadIdx.x & 63;
  if (node >= Ns) return;
  uint4 raw = *reinterpret_cast<const uint4*>(Hs + (size_t)node * 512 + lane * 8);
  float xv[8];
  xv[0] = b2f(raw.x & 0xffffu); xv[1] = b2f(raw.x >> 16);
  xv[2] = b2f(raw.y & 0xffffu); xv[3] = b2f(raw.y >> 16);
  xv[4] = b2f(raw.z & 0xffffu); xv[5] = b2f(raw.z >> 16);
  xv[6] = b2f(raw.w & 0xffffu); xv[7] = b2f(raw.w >> 16);
  bool nR = node < Nd;
  float a[4], b[4];
#pragma unroll
  for (int h = 0; h < 4; ++h) {
    const float* wp = wlr + h * 512 + lane * 8;
    float4 w0 = *reinterpret_cast<const float4*>(wp);
    float4 w1 = *reinterpret_cast<const float4*>(wp + 4);
    a[h] = xv[0]*w0.x + xv[1]*w0.y + xv[2]*w0.z + xv[3]*w0.w +
           xv[4]*w1.x + xv[5]*w1.y + xv[6]*w1.z + xv[7]*w1.w;
    b[h] = 0.f;
    if (nR) {
      const float* wq = wlr + 2048 + h * 512 + lane * 8;
      float4 v0 = *reinterpret_cast<const float4*>(wq);
      float4 v1 = *reinterpret_cast<const float4*>(wq + 4);
      b[h] = xv[0]*v0.x + xv[1]*v0.y + xv[2]*v0.z + xv[3]*v0.w +
             xv[4]*v1.x + xv[5]*v1.y + xv[6]*v1.z + xv[7]*v1.w;
    }
  }
#pragma unroll
  for (int h = 0; h < 4; ++h) {
    for (int off = 32; off > 0; off >>= 1) {
      a[h] += __shfl_xor(a[h], off);
      b[h] += __shfl_xor(b[h], off);
    }
  }
  if (lane == 0) {
#pragma unroll
    for (int h = 0; h < 4; ++h) ell[(size_t)node * 4 + h] = a[h];
    if (nR) {
#pragma unroll
      for (int h = 0; h < 4; ++h) err[(size_t)node * 4 + h] = b[h];
    }
  }
}

__global__ void k_count(const int* __restrict__ dst, int* __restrict__ cnt, int E) {
  int e = blockIdx.x * 256 + threadIdx.x;
  if (e < E) atomicAdd(&cnt[dst[e]], 1);
}

// single-block scan, wave-shuffle based (3 barriers per 1024 chunk)
__global__ __launch_bounds__(1024) void k_scan(const int* __restrict__ cnt,
                                               int* __restrict__ rowptr,
                                               int* __restrict__ cursor, int Nd) {
  __shared__ int wsum[16];
  __shared__ int carry_s;
  int t = threadIdx.x, wid = t >> 6, lane = t & 63;
  if (t == 0) { carry_s = 0; rowptr[0] = 0; }
  __syncthreads();
  for (int base = 0; base < Nd; base += 1024) {
    int i = base + t;
    int v = (i < Nd) ? cnt[i] : 0;
    int s = v;
    for (int off = 1; off < 64; off <<= 1) {
      int u = __shfl_up(s, off);
      if (lane >= off) s += u;
    }
    int carry = carry_s;
    if (lane == 63) wsum[wid] = s;
    __syncthreads();
    int woff = 0;
    for (int w2 = 0; w2 < wid; ++w2) woff += wsum[w2];
    int inc = s + woff + carry;
    if (i < Nd) { rowptr[i + 1] = inc; cursor[i] = inc - v; }
    __syncthreads();
    if (t == 1023) carry_s = inc;
    __syncthreads();
  }
}

__global__ void k_fill_u32(unsigned* __restrict__ p, unsigned v, int n) {
  int i = blockIdx.x * 256 + threadIdx.x;
  if (i < n) p[i] = v;
}

__global__ void k_edge_max(const int* __restrict__ src, const int* __restrict__ dst,
                           const float* __restrict__ ell, const float* __restrict__ err,
                           unsigned* __restrict__ menc, int E) {
  int e = blockIdx.x * 256 + threadIdx.x;
  if (e >= E) return;
  int s = src[e], d = dst[e];
  float4 el4 = *reinterpret_cast<const float4*>(ell + (size_t)s * 4);
  float4 er4 = *reinterpret_cast<const float4*>(err + (size_t)d * 4);
  unsigned* mb = menc + (size_t)d * 4;
  atomicMax(mb + 0, fenc(lrelu(el4.x + er4.x)));
  atomicMax(mb + 1, fenc(lrelu(el4.y + er4.y)));
  atomicMax(mb + 2, fenc(lrelu(el4.z + er4.z)));
  atomicMax(mb + 3, fenc(lrelu(el4.w + er4.w)));
}

__global__ void k_edge_exp(const int* __restrict__ src, const int* __restrict__ dst,
                           const float* __restrict__ ell, const float* __restrict__ err,
                           const unsigned* __restrict__ menc, float* __restrict__ sbuf,
                           int* __restrict__ cursor, int* __restrict__ colv,
                           float* __restrict__ exs, int E) {
  int e = blockIdx.x * 256 + threadIdx.x;
  if (e >= E) return;
  int s = src[e], d = dst[e];
  int slot = atomicAdd(&cursor[d], 1);
  colv[slot] = s;
  float4 el4 = *reinterpret_cast<const float4*>(ell + (size_t)s * 4);
  float4 er4 = *reinterpret_cast<const float4*>(err + (size_t)d * 4);
  const unsigned* mb = menc + (size_t)d * 4;
  float w0 = __expf(lrelu(el4.x + er4.x) - fdec(mb[0]));
  float w1 = __expf(lrelu(el4.y + er4.y) - fdec(mb[1]));
  float w2 = __expf(lrelu(el4.z + er4.z) - fdec(mb[2]));
  float w3 = __expf(lrelu(el4.w + er4.w) - fdec(mb[3]));
  *reinterpret_cast<float4*>(exs + (size_t)slot * 4) = make_float4(w0, w1, w2, w3);
  float* sb = sbuf + (size_t)d * 4;
  atomicAdd(sb + 0, w0);
  atomicAdd(sb + 1, w1);
  atomicAdd(sb + 2, w2);
  atomicAdd(sb + 3, w3);
}

// bf16 weighted gather: Z[n,h,c] = (1/s[n,h]) * sum_e ex_e * Hs[src_e,c]
// FIN/4 threads, each thread owns 4 columns (ushort4 loads).
template <int FIN>
__global__ __launch_bounds__(FIN / 4) void k_gather_bf(
    const unsigned short* __restrict__ Hs, const int* __restrict__ rowptr,
    const int* __restrict__ colv, const float* __restrict__ exs,
    const float* __restrict__ sbuf, unsigned short* __restrict__ Z) {
  constexpr int TB = FIN / 4;
  int n = blockIdx.x, t = threadIdx.x;
  int beg = rowptr[n], end = rowptr[n + 1];
  float inv[4];
#pragma unroll
  for (int h = 0; h < 4; ++h) inv[h] = 1.f / fmaxf(sbuf[(size_t)n * 4 + h], 1e-9f);
  float acc[4][4] = {};
  __shared__ float wsm[256];
  __shared__ int csm[64];
  for (int c0 = beg; c0 < end; c0 += 64) {
    int cnt = min(64, end - c0);
    __syncthreads();
    for (int i = t; i < cnt; i += TB) csm[i] = colv[c0 + i];
    for (int i = t; i < cnt * 4; i += TB) wsm[i] = exs[(size_t)c0 * 4 + i];
    __syncthreads();
    for (int j = 0; j < cnt; ++j) {
      uint2 raw = *reinterpret_cast<const uint2*>(Hs + (size_t)csm[j] * FIN + t * 4);
      float x0 = b2f(raw.x & 0xffffu), x1 = b2f(raw.x >> 16);
      float x2 = b2f(raw.y & 0xffffu), x3 = b2f(raw.y >> 16);
#pragma unroll
      for (int h = 0; h < 4; ++h) {
        float w = wsm[j * 4 + h];
        acc[h][0] = fmaf(w, x0, acc[h][0]);
        acc[h][1] = fmaf(w, x1, acc[h][1]);
        acc[h][2] = fmaf(w, x2, acc[h][2]);
        acc[h][3] = fmaf(w, x3, acc[h][3]);
      }
    }
  }
#pragma unroll
  for (int h = 0; h < 4; ++h) {
    ushort4 o;
    o.x = f2b(acc[h][0] * inv[h]); o.y = f2b(acc[h][1] * inv[h]);
    o.z = f2b(acc[h][2] * inv[h]); o.w = f2b(acc[h][3] * inv[h]);
    *reinterpret_cast<ushort4*>(Z + (size_t)n * 4 * FIN + h * FIN + t * 4) = o;
  }
}

// bf16 MFMA GEMM, per-head: out[m, h*Fout+n] = (Z_h @ W_h^T)[m,n] + bias  (opt ELU)
// 128x64 tile, BK=64, 256 thr (4 waves, each 32 rows x 64 cols), 16x16x32 MFMA.
template <bool ACT, bool OUTBF>
__global__ __launch_bounds__(256) void k_gemm_mfma(
    const unsigned short* __restrict__ Zb, const unsigned short* __restrict__ Wb,
    const float* __restrict__ bias, void* __restrict__ outv,
    int M, int N, int K) {
  int h = blockIdx.z;
  __shared__ unsigned short As[128][72];  // pad 64->72 (row 144B, 16B aligned)
  __shared__ unsigned short Bs[64][72];
  int tid = threadIdx.x;
  int bm = blockIdx.x * 128, bn = blockIdx.y * 64;
  int lda = 4 * K;
  const unsigned short* Ag = Zb + (size_t)h * K;
  const unsigned short* Bg = Wb + (size_t)h * N * K;
  int ar = tid >> 3, aseg = tid & 7;  // staging: 32 rows x 8 segs per pass
  int w = tid >> 6, lane = tid & 63;
  f32x4 acc[2][4] = {};
  for (int k0 = 0; k0 < K; k0 += 64) {
    __syncthreads();
#pragma unroll
    for (int i = 0; i < 4; ++i) {
      int r = ar + i * 32;
      int gm = bm + r;
      uint4 v = make_uint4(0u, 0u, 0u, 0u);
      if (gm < M) v = *reinterpret_cast<const uint4*>(Ag + (size_t)gm * lda + k0 + aseg * 8);
      *reinterpret_cast<uint4*>(&As[r][aseg * 8]) = v;
    }
#pragma unroll
    for (int i = 0; i < 2; ++i) {
      int r = ar + i * 32;
      int gn = bn + r;
      uint4 v = make_uint4(0u, 0u, 0u, 0u);
      if (gn < N) v = *reinterpret_cast<const uint4*>(Bg + (size_t)gn * K + k0 + aseg * 8);
      *reinterpret_cast<uint4*>(&Bs[r][aseg * 8]) = v;
    }
    __syncthreads();
    int row0 = w * 32;
    bf8_t afr[2][2], bfr[2][4];
#pragma unroll
    for (int ks = 0; ks < 2; ++ks) {
#pragma unroll
      for (int fm = 0; fm < 2; ++fm)
        afr[ks][fm] = *reinterpret_cast<const bf8_t*>(
            &As[row0 + fm * 16 + (lane & 15)][ks * 32 + (lane >> 4) * 8]);
#pragma unroll
      for (int fn = 0; fn < 4; ++fn)
        bfr[ks][fn] = *reinterpret_cast<const bf8_t*>(
            &Bs[fn * 16 + (lane & 15)][ks * 32 + (lane >> 4) * 8]);
    }
#pragma unroll
    for (int ks = 0; ks < 2; ++ks)
#pragma unroll
      for (int fm = 0; fm < 2; ++fm)
#pragma unroll
        for (int fn = 0; fn < 4; ++fn)
          acc[fm][fn] = __builtin_amdgcn_mfma_f32_16x16x32_bf16(
              afr[ks][fm], bfr[ks][fn], acc[fm][fn], 0, 0, 0);
  }
  int ldo = 4 * N;
#pragma unroll
  for (int fm = 0; fm < 2; ++fm) {
#pragma unroll
    for (int fn = 0; fn < 4; ++fn) {
      int colb = bn + fn * 16 + (lane & 15);
      if (colb >= N) continue;
      float bv = bias[h * N + colb];
#pragma unroll
      for (int j = 0; j < 4; ++j) {
        int rowb = bm + w * 32 + fm * 16 + (lane >> 4) * 4 + j;
        if (rowb >= M) continue;
        float v = acc[fm][fn][j] + bv;
        if (ACT) v = v > 0.f ? v : expm1f(v);
        size_t off = (size_t)rowb * ldo + (size_t)h * N + colb;
        if (OUTBF) ((unsigned short*)outv)[off] = f2b(v);
        else ((float*)outv)[off] = v;
      }
    }
  }
}

// mean over 4 heads (C=47) + log_softmax; one wave per node
__global__ __launch_bounds__(256) void k_mean_lsm(const float* __restrict__ rst2,
                                                  float* __restrict__ out, int Nd) {
  int node = blockIdx.x * 4 + (threadIdx.x >> 6);
  int lane = threadIdx.x & 63;
  if (node >= Nd) return;
  const float* r = rst2 + (size_t)node * 188;
  float vv = 0.f;
  if (lane < 47)
    vv = 0.25f * (r[lane] + r[47 + lane] + r[94 + lane] + r[141 + lane]);
  float m = (lane < 47) ? vv : -INFINITY;
  for (int off = 32; off > 0; off >>= 1) m = fmaxf(m, __shfl_xor(m, off));
  float ex = (lane < 47) ? __expf(vv - m) : 0.f;
  float ss = ex;
  for (int off = 32; off > 0; off >>= 1) ss += __shfl_xor(ss, off);
  if (lane < 47) out[(size_t)node * 47 + lane] = vv - m - logf(ss);
}

extern "C" void kernel_launch(void* const* d_in, const int* in_sizes, int n_in,
                              void* d_out, int out_size, void* d_ws, size_t ws_size,
                              hipStream_t stream) {
  (void)in_sizes; (void)n_in; (void)out_size; (void)ws_size;
  const float* x = (const float*)d_in[0];
  const int* srcs[3] = {(const int*)d_in[1], (const int*)d_in[3], (const int*)d_in[5]};
  const int* dsts[3] = {(const int*)d_in[2], (const int*)d_in[4], (const int*)d_in[6]};
  const float* Wsrc[3] = {(const float*)d_in[7], (const float*)d_in[12], (const float*)d_in[17]};
  const float* Wdst[3] = {(const float*)d_in[8], (const float*)d_in[13], (const float*)d_in[18]};
  const float* al[3]   = {(const float*)d_in[9], (const float*)d_in[14], (const float*)d_in[19]};
  const float* ar[3]   = {(const float*)d_in[10], (const float*)d_in[15], (const float*)d_in[20]};
  const float* bb[3]   = {(const float*)d_in[11], (const float*)d_in[16], (const float*)d_in[21]};

  char* p = (char*)d_ws;
  auto alloc = [&](size_t bytes) -> void* {
    void* r = (void*)p;
    p += (bytes + 255) & ~(size_t)255;
    return r;
  };
  unsigned short* xbf = (unsigned short*)alloc((size_t)150000 * 256 * 2);  // 76.8MB
  unsigned short* zbf = (unsigned short*)alloc((size_t)25000 * 1024 * 2);  // 51.2MB
  unsigned short* h1  = (unsigned short*)alloc((size_t)25000 * 512 * 2);
  unsigned short* h2  = (unsigned short*)alloc((size_t)6000 * 512 * 2);
  float* rst2   = (float*)alloc((size_t)1024 * 188 * 4);
  unsigned short* Wb0 = (unsigned short*)alloc((size_t)512 * 256 * 2);
  unsigned short* Wb1 = (unsigned short*)alloc((size_t)512 * 512 * 2);
  unsigned short* Wb2 = (unsigned short*)alloc((size_t)188 * 512 * 2);
  float* ell    = (float*)alloc((size_t)150000 * 4 * 4);
  float* err    = (float*)alloc((size_t)25000 * 4 * 4);
  unsigned* menc= (unsigned*)alloc((size_t)25000 * 4 * 4);
  float* sbuf   = (float*)alloc((size_t)25000 * 4 * 4);
  float* exs    = (float*)alloc((size_t)375000 * 4 * 4);
  int* cnt      = (int*)alloc((size_t)25000 * 4);
  int* rowptr   = (int*)alloc((size_t)25001 * 4);
  int* cursor   = (int*)alloc((size_t)25000 * 4);
  int* colv     = (int*)alloc((size_t)375000 * 4);
  float* wlr    = (float*)alloc((size_t)8 * 512 * 4);

  // weight conversions (once, tiny)
  k_cvt_bf<<<(512 * 256 + 255) / 256, 256, 0, stream>>>(Wsrc[0], Wb0, 512 * 256);
  k_cvt_bf<<<(512 * 512 + 255) / 256, 256, 0, stream>>>(Wsrc[1], Wb1, 512 * 512);
  k_cvt_bf<<<(188 * 512 + 255) / 256, 256, 0, stream>>>(Wsrc[2], Wb2, 188 * 512);

  const unsigned short* Hbf[3] = {xbf, h1, h2};
  const unsigned short* Wbf[3] = {Wb0, Wb1, Wb2};

  for (int l = 0; l < 3; ++l) {
    int Ns = L_NS[l], Nd = L_ND[l], E = L_E[l], Fin = L_FIN[l], Fout = L_FOUT[l];
    k_build_wlr<<<(8 * Fin + 255) / 256, 256, 0, stream>>>(Wsrc[l], Wdst[l], al[l], ar[l], wlr, Fin, Fout);
    if (l == 0)
      k_dot_cvt<<<(Ns + 3) / 4, 256, 0, stream>>>(x, wlr, xbf, ell, err, Ns, Nd);
    else
      k_dot_bf<<<(Ns + 3) / 4, 256, 0, stream>>>(Hbf[l], wlr, ell, err, Ns, Nd);
    hipMemsetAsync(cnt, 0, (size_t)Nd * sizeof(int), stream);
    k_count<<<(E + 255) / 256, 256, 0, stream>>>(dsts[l], cnt, E);
    k_scan<<<1, 1024, 0, stream>>>(cnt, rowptr, cursor, Nd);
    k_fill_u32<<<(Nd * 4 + 255) / 256, 256, 0, stream>>>(menc, 0x007FFFFFu /* enc(-inf) */, Nd * 4);
    k_edge_max<<<(E + 255) / 256, 256, 0, stream>>>(srcs[l], dsts[l], ell, err, menc, E);
    hipMemsetAsync(sbuf, 0, (size_t)Nd * 4 * sizeof(float), stream);
    k_edge_exp<<<(E + 255) / 256, 256, 0, stream>>>(srcs[l], dsts[l], ell, err, menc, sbuf, cursor, colv, exs, E);
    if (Fin == 256)
      k_gather_bf<256><<<Nd, 64, 0, stream>>>(Hbf[l], rowptr, colv, exs, sbuf, zbf);
    else
      k_gather_bf<512><<<Nd, 128, 0, stream>>>(Hbf[l], rowptr, colv, exs, sbuf, zbf);
    dim3 g((Nd + 127) / 128, (Fout + 63) / 64, 4);
    if (l == 0)
      k_gemm_mfma<true, true><<<g, 256, 0, stream>>>(zbf, Wbf[l], bb[l], h1, Nd, Fout, Fin);
    else if (l == 1)
      k_gemm_mfma<true, true><<<g, 256, 0, stream>>>(zbf, Wbf[l], bb[l], h2, Nd, Fout, Fin);
    else
      k_gemm_mfma<false, false><<<g, 256, 0, stream>>>(zbf, Wbf[l], bb[l], rst2, Nd, Fout, Fin);
  }
  k_mean_lsm<<<(1024 + 3) / 4, 256, 0, stream>>>(rst2, (float*)d_out, 1024);
}

// Round 3
// 454.337 us; speedup vs baseline: 1.9649x; 1.5666x over previous
//
#include <hip/hip_runtime.h>
#include <math.h>

// ---------------------------------------------------------------------------
// GAT 3-layer pipeline. bf16 features + MFMA GEMMs, fused CSR edge-softmax.
//   el = h @ wl.T, wl[h,:] = al[h,:] @ Wsrc_h   (no fs materialization)
//   agg = (softmax-weighted sum of raw feats) @ Wsrc_h.T  (aggregate first)
// CSR built once upfront (graph topology is input-static); per-dst gather
// kernel computes max/exp/sum in-block -> zero per-edge float atomics.
// ---------------------------------------------------------------------------

#define E0 375000
#define E1 90000
#define E2 10240
#define ETOT (E0 + E1 + E2)

static const int L_NS[3]   = {150000, 25000, 6000};
static const int L_ND[3]   = {25000, 6000, 1024};
static const int L_FIN[3]  = {256, 512, 512};
static const int L_FOUT[3] = {128, 128, 47};

typedef short bf8_t __attribute__((ext_vector_type(8)));
typedef float f32x4 __attribute__((ext_vector_type(4)));

__device__ __forceinline__ float lrelu(float v) { return v >= 0.f ? v : 0.2f * v; }
__device__ __forceinline__ unsigned short f2b(float f) {
  unsigned u = __float_as_uint(f);
  unsigned r = u + 0x7fffu + ((u >> 16) & 1u);
  return (unsigned short)(r >> 16);
}
__device__ __forceinline__ float b2f(unsigned v) {  // low 16 bits
  return __uint_as_float(v << 16);
}

// wlr[0..4*Fin) = wl (al . Wsrc), wlr[4*Fin..8*Fin) = wr (ar . Wdst)   (fp32)
__global__ void k_build_wlr(const float* __restrict__ Wsrc, const float* __restrict__ Wdst,
                            const float* __restrict__ al, const float* __restrict__ ar,
                            float* __restrict__ wlr, int Fin, int Fout) {
  int idx = blockIdx.x * 256 + threadIdx.x;
  if (idx >= 8 * Fin) return;
  int which = idx / (4 * Fin);
  int rem = idx - which * 4 * Fin;
  int h = rem / Fin, k = rem - h * Fin;
  const float* W = which ? Wdst : Wsrc;
  const float* a = which ? ar : al;
  float acc = 0.f;
  for (int d = 0; d < Fout; ++d)
    acc += a[h * Fout + d] * W[(size_t)(h * Fout + d) * Fin + k];
  wlr[idx] = acc;
}

__global__ void k_cvt_bf(const float* __restrict__ in, unsigned short* __restrict__ out, int n) {
  int i = blockIdx.x * 256 + threadIdx.x;
  if (i < n) out[i] = f2b(in[i]);
}

// ---------------- CSR build (all 3 layers, once) ----------------

__global__ void k_count_all(const int* __restrict__ d0, const int* __restrict__ d1,
                            const int* __restrict__ d2, int* __restrict__ c0,
                            int* __restrict__ c1, int* __restrict__ c2,
                            int* __restrict__ r) {
  int g = blockIdx.x * 256 + threadIdx.x;
  if (g >= ETOT) return;
  const int* d; int* c; int e;
  if (g < E0) { e = g; d = d0; c = c0; }
  else if (g < E0 + E1) { e = g - E0; d = d1; c = c1; }
  else { e = g - E0 - E1; d = d2; c = c2; }
  r[g] = atomicAdd(&c[d[e]], 1);
}

// 3 blocks, one per layer; 4 elems/thread chunked scan
__global__ __launch_bounds__(1024) void k_scan3(
    const int* __restrict__ c0, int* __restrict__ r0, int n0,
    const int* __restrict__ c1, int* __restrict__ r1, int n1,
    const int* __restrict__ c2, int* __restrict__ r2, int n2) {
  const int* cnt; int* rowptr; int Nd;
  if (blockIdx.x == 0) { cnt = c0; rowptr = r0; Nd = n0; }
  else if (blockIdx.x == 1) { cnt = c1; rowptr = r1; Nd = n1; }
  else { cnt = c2; rowptr = r2; Nd = n2; }
  __shared__ int wsum[16];
  __shared__ int carry_s;
  int t = threadIdx.x, wid = t >> 6, lane = t & 63;
  if (t == 0) { carry_s = 0; rowptr[0] = 0; }
  __syncthreads();
  for (int base = 0; base < Nd; base += 4096) {
    int i0 = base + t * 4;
    int v0 = (i0 + 0 < Nd) ? cnt[i0 + 0] : 0;
    int v1 = (i0 + 1 < Nd) ? cnt[i0 + 1] : 0;
    int v2 = (i0 + 2 < Nd) ? cnt[i0 + 2] : 0;
    int v3 = (i0 + 3 < Nd) ? cnt[i0 + 3] : 0;
    int ts = v0 + v1 + v2 + v3;
    int s = ts;
    for (int off = 1; off < 64; off <<= 1) {
      int u = __shfl_up(s, off);
      if (lane >= off) s += u;
    }
    if (lane == 63) wsum[wid] = s;
    __syncthreads();
    int woff = carry_s;
    for (int w2 = 0; w2 < wid; ++w2) woff += wsum[w2];
    int excl = woff + s - ts;
    int p0 = excl + v0, p1 = p0 + v1, p2 = p1 + v2, p3 = p2 + v3;
    if (i0 + 0 < Nd) rowptr[i0 + 1] = p0;
    if (i0 + 1 < Nd) rowptr[i0 + 2] = p1;
    if (i0 + 2 < Nd) rowptr[i0 + 3] = p2;
    if (i0 + 3 < Nd) rowptr[i0 + 4] = p3;
    __syncthreads();
    if (t == 1023) carry_s = p3;
  }
}

__global__ void k_scatter_all(
    const int* __restrict__ s0, const int* __restrict__ d0, const int* __restrict__ rp0, int* __restrict__ cv0,
    const int* __restrict__ s1, const int* __restrict__ d1, const int* __restrict__ rp1, int* __restrict__ cv1,
    const int* __restrict__ s2, const int* __restrict__ d2, const int* __restrict__ rp2, int* __restrict__ cv2,
    const int* __restrict__ r) {
  int g = blockIdx.x * 256 + threadIdx.x;
  if (g >= ETOT) return;
  const int* s; const int* d; const int* rp; int* cv; int e;
  if (g < E0) { e = g; s = s0; d = d0; rp = rp0; cv = cv0; }
  else if (g < E0 + E1) { e = g - E0; s = s1; d = d1; rp = rp1; cv = cv1; }
  else { e = g - E0 - E1; s = s2; d = d2; rp = rp2; cv = cv2; }
  cv[rp[d[e]] + r[g]] = s[e];
}

// ---------------- per-layer feature kernels ----------------

// layer 0: fp32 x -> ell/err + bf16 copy. Fin=256, one wave per node.
__global__ __launch_bounds__(256) void k_dot_cvt(
    const float* __restrict__ x, const float* __restrict__ wlr,
    unsigned short* __restrict__ xbf, float* __restrict__ ell, float* __restrict__ err,
    int Ns, int Nd) {
  int node = blockIdx.x * 4 + (threadIdx.x >> 6);
  int lane = threadIdx.x & 63;
  if (node >= Ns) return;
  float4 xv = *reinterpret_cast<const float4*>(x + (size_t)node * 256 + lane * 4);
  ushort4 ub;
  ub.x = f2b(xv.x); ub.y = f2b(xv.y); ub.z = f2b(xv.z); ub.w = f2b(xv.w);
  *reinterpret_cast<ushort4*>(xbf + (size_t)node * 256 + lane * 4) = ub;
  bool nR = node < Nd;
  float a[4], b[4];
#pragma unroll
  for (int h = 0; h < 4; ++h) {
    float4 wv = *reinterpret_cast<const float4*>(wlr + h * 256 + lane * 4);
    a[h] = xv.x * wv.x + xv.y * wv.y + xv.z * wv.z + xv.w * wv.w;
    b[h] = 0.f;
    if (nR) {
      float4 w2 = *reinterpret_cast<const float4*>(wlr + 1024 + h * 256 + lane * 4);
      b[h] = xv.x * w2.x + xv.y * w2.y + xv.z * w2.z + xv.w * w2.w;
    }
  }
#pragma unroll
  for (int h = 0; h < 4; ++h) {
    for (int off = 32; off > 0; off >>= 1) {
      a[h] += __shfl_xor(a[h], off);
      b[h] += __shfl_xor(b[h], off);
    }
  }
  if (lane == 0) {
#pragma unroll
    for (int h = 0; h < 4; ++h) ell[(size_t)node * 4 + h] = a[h];
    if (nR) {
#pragma unroll
      for (int h = 0; h < 4; ++h) err[(size_t)node * 4 + h] = b[h];
    }
  }
}

// layers 1/2: bf16 features, Fin=512, one wave per node.
__global__ __launch_bounds__(256) void k_dot_bf(
    const unsigned short* __restrict__ Hs, const float* __restrict__ wlr,
    float* __restrict__ ell, float* __restrict__ err, int Ns, int Nd) {
  int node = blockIdx.x * 4 + (threadIdx.x >> 6);
  int lane = threadIdx.x & 63;
  if (node >= Ns) return;
  uint4 raw = *reinterpret_cast<const uint4*>(Hs + (size_t)node * 512 + lane * 8);
  float xv[8];
  xv[0] = b2f(raw.x & 0xffffu); xv[1] = b2f(raw.x >> 16);
  xv[2] = b2f(raw.y & 0xffffu); xv[3] = b2f(raw.y >> 16);
  xv[4] = b2f(raw.z & 0xffffu); xv[5] = b2f(raw.z >> 16);
  xv[6] = b2f(raw.w & 0xffffu); xv[7] = b2f(raw.w >> 16);
  bool nR = node < Nd;
  float a[4], b[4];
#pragma unroll
  for (int h = 0; h < 4; ++h) {
    const float* wp = wlr + h * 512 + lane * 8;
    float4 w0 = *reinterpret_cast<const float4*>(wp);
    float4 w1 = *reinterpret_cast<const float4*>(wp + 4);
    a[h] = xv[0]*w0.x + xv[1]*w0.y + xv[2]*w0.z + xv[3]*w0.w +
           xv[4]*w1.x + xv[5]*w1.y + xv[6]*w1.z + xv[7]*w1.w;
    b[h] = 0.f;
    if (nR) {
      const float* wq = wlr + 2048 + h * 512 + lane * 8;
      float4 v0 = *reinterpret_cast<const float4*>(wq);
      float4 v1 = *reinterpret_cast<const float4*>(wq + 4);
      b[h] = xv[0]*v0.x + xv[1]*v0.y + xv[2]*v0.z + xv[3]*v0.w +
             xv[4]*v1.x + xv[5]*v1.y + xv[6]*v1.z + xv[7]*v1.w;
    }
  }
#pragma unroll
  for (int h = 0; h < 4; ++h) {
    for (int off = 32; off > 0; off >>= 1) {
      a[h] += __shfl_xor(a[h], off);
      b[h] += __shfl_xor(b[h], off);
    }
  }
  if (lane == 0) {
#pragma unroll
    for (int h = 0; h < 4; ++h) ell[(size_t)node * 4 + h] = a[h];
    if (nR) {
#pragma unroll
      for (int h = 0; h < 4; ++h) err[(size_t)node * 4 + h] = b[h];
    }
  }
}

// fused per-dst softmax + weighted bf16 feature gather.
// block = one dst node; TB=FIN/4 threads, each owns 4 feature cols.
// pass1: walk segment, e=lrelu(ell[src]+err[n]) (ell is L2-resident),
//        cache e in LDS (CAP), block-reduce max.
// pass2: w=exp(e-m); every thread accumulates identical denom s (no reduce)
//        and its 4 cols of sum_e w*Hs[src]. Write Z = acc/s in bf16.
template <int FIN>
__global__ __launch_bounds__(FIN / 4) void k_gather_fused(
    const unsigned short* __restrict__ Hs, const float* __restrict__ ell,
    const float* __restrict__ err, const int* __restrict__ rowptr,
    const int* __restrict__ colv, unsigned short* __restrict__ Z) {
  constexpr int TB = FIN / 4;
  constexpr int NW = TB / 64;
  constexpr int CAP = 256;
  int n = blockIdx.x, t = threadIdx.x;
  int beg = rowptr[n], cnt = rowptr[n + 1] - beg;
  float4 er4 = *reinterpret_cast<const float4*>(err + (size_t)n * 4);
  __shared__ float4 esm[CAP];
  __shared__ int csm[CAP];
  __shared__ float4 wred[NW];
  float m0 = -INFINITY, m1 = -INFINITY, m2 = -INFINITY, m3 = -INFINITY;
  for (int i = t; i < cnt; i += TB) {
    int c = colv[beg + i];
    float4 el4 = *reinterpret_cast<const float4*>(ell + (size_t)c * 4);
    float4 e4;
    e4.x = lrelu(el4.x + er4.x); e4.y = lrelu(el4.y + er4.y);
    e4.z = lrelu(el4.z + er4.z); e4.w = lrelu(el4.w + er4.w);
    if (i < CAP) { csm[i] = c; esm[i] = e4; }
    m0 = fmaxf(m0, e4.x); m1 = fmaxf(m1, e4.y);
    m2 = fmaxf(m2, e4.z); m3 = fmaxf(m3, e4.w);
  }
  for (int off = 32; off > 0; off >>= 1) {
    m0 = fmaxf(m0, __shfl_xor(m0, off));
    m1 = fmaxf(m1, __shfl_xor(m1, off));
    m2 = fmaxf(m2, __shfl_xor(m2, off));
    m3 = fmaxf(m3, __shfl_xor(m3, off));
  }
  if constexpr (NW > 1) {
    if ((t & 63) == 0) wred[t >> 6] = make_float4(m0, m1, m2, m3);
  }
  __syncthreads();  // esm/csm (+wred) visible
  if constexpr (NW > 1) {
    float4 wa = wred[0], wb = wred[1];
    m0 = fmaxf(wa.x, wb.x); m1 = fmaxf(wa.y, wb.y);
    m2 = fmaxf(wa.z, wb.z); m3 = fmaxf(wa.w, wb.w);
  }
  float s0 = 0.f, s1 = 0.f, s2 = 0.f, s3 = 0.f;
  float acc[4][4] = {};
  for (int j = 0; j < cnt; ++j) {
    float4 e4; int c;
    if (j < CAP) { e4 = esm[j]; c = csm[j]; }
    else {
      c = colv[beg + j];
      float4 el4 = *reinterpret_cast<const float4*>(ell + (size_t)c * 4);
      e4.x = lrelu(el4.x + er4.x); e4.y = lrelu(el4.y + er4.y);
      e4.z = lrelu(el4.z + er4.z); e4.w = lrelu(el4.w + er4.w);
    }
    float w0 = __expf(e4.x - m0), w1 = __expf(e4.y - m1);
    float w2 = __expf(e4.z - m2), w3 = __expf(e4.w - m3);
    s0 += w0; s1 += w1; s2 += w2; s3 += w3;
    ushort4 xr = *reinterpret_cast<const ushort4*>(Hs + (size_t)c * FIN + t * 4);
    float x0 = b2f(xr.x), x1 = b2f(xr.y), x2 = b2f(xr.z), x3 = b2f(xr.w);
    acc[0][0] = fmaf(w0, x0, acc[0][0]); acc[0][1] = fmaf(w0, x1, acc[0][1]);
    acc[0][2] = fmaf(w0, x2, acc[0][2]); acc[0][3] = fmaf(w0, x3, acc[0][3]);
    acc[1][0] = fmaf(w1, x0, acc[1][0]); acc[1][1] = fmaf(w1, x1, acc[1][1]);
    acc[1][2] = fmaf(w1, x2, acc[1][2]); acc[1][3] = fmaf(w1, x3, acc[1][3]);
    acc[2][0] = fmaf(w2, x0, acc[2][0]); acc[2][1] = fmaf(w2, x1, acc[2][1]);
    acc[2][2] = fmaf(w2, x2, acc[2][2]); acc[2][3] = fmaf(w2, x3, acc[2][3]);
    acc[3][0] = fmaf(w3, x0, acc[3][0]); acc[3][1] = fmaf(w3, x1, acc[3][1]);
    acc[3][2] = fmaf(w3, x2, acc[3][2]); acc[3][3] = fmaf(w3, x3, acc[3][3]);
  }
  float inv[4];
  inv[0] = 1.f / fmaxf(s0, 1e-9f); inv[1] = 1.f / fmaxf(s1, 1e-9f);
  inv[2] = 1.f / fmaxf(s2, 1e-9f); inv[3] = 1.f / fmaxf(s3, 1e-9f);
#pragma unroll
  for (int h = 0; h < 4; ++h) {
    ushort4 o;
    o.x = f2b(acc[h][0] * inv[h]); o.y = f2b(acc[h][1] * inv[h]);
    o.z = f2b(acc[h][2] * inv[h]); o.w = f2b(acc[h][3] * inv[h]);
    *reinterpret_cast<ushort4*>(Z + (size_t)n * 4 * FIN + h * FIN + t * 4) = o;
  }
}

// bf16 MFMA GEMM, per-head: out[m, h*Fout+n] = (Z_h @ W_h^T)[m,n] + bias  (opt ELU)
// 128x64 tile, BK=64, 256 thr (4 waves), 16x16x32 MFMA.
template <bool ACT, bool OUTBF>
__global__ __launch_bounds__(256) void k_gemm_mfma(
    const unsigned short* __restrict__ Zb, const unsigned short* __restrict__ Wb,
    const float* __restrict__ bias, void* __restrict__ outv,
    int M, int N, int K) {
  int h = blockIdx.z;
  __shared__ unsigned short As[128][72];
  __shared__ unsigned short Bs[64][72];
  int tid = threadIdx.x;
  int bm = blockIdx.x * 128, bn = blockIdx.y * 64;
  int lda = 4 * K;
  const unsigned short* Ag = Zb + (size_t)h * K;
  const unsigned short* Bg = Wb + (size_t)h * N * K;
  int ar = tid >> 3, aseg = tid & 7;
  int w = tid >> 6, lane = tid & 63;
  f32x4 acc[2][4] = {};
  for (int k0 = 0; k0 < K; k0 += 64) {
    __syncthreads();
#pragma unroll
    for (int i = 0; i < 4; ++i) {
      int r = ar + i * 32;
      int gm = bm + r;
      uint4 v = make_uint4(0u, 0u, 0u, 0u);
      if (gm < M) v = *reinterpret_cast<const uint4*>(Ag + (size_t)gm * lda + k0 + aseg * 8);
      *reinterpret_cast<uint4*>(&As[r][aseg * 8]) = v;
    }
#pragma unroll
    for (int i = 0; i < 2; ++i) {
      int r = ar + i * 32;
      int gn = bn + r;
      uint4 v = make_uint4(0u, 0u, 0u, 0u);
      if (gn < N) v = *reinterpret_cast<const uint4*>(Bg + (size_t)gn * K + k0 + aseg * 8);
      *reinterpret_cast<uint4*>(&Bs[r][aseg * 8]) = v;
    }
    __syncthreads();
    int row0 = w * 32;
    bf8_t afr[2][2], bfr[2][4];
#pragma unroll
    for (int ks = 0; ks < 2; ++ks) {
#pragma unroll
      for (int fm = 0; fm < 2; ++fm)
        afr[ks][fm] = *reinterpret_cast<const bf8_t*>(
            &As[row0 + fm * 16 + (lane & 15)][ks * 32 + (lane >> 4) * 8]);
#pragma unroll
      for (int fn = 0; fn < 4; ++fn)
        bfr[ks][fn] = *reinterpret_cast<const bf8_t*>(
            &Bs[fn * 16 + (lane & 15)][ks * 32 + (lane >> 4) * 8]);
    }
#pragma unroll
    for (int ks = 0; ks < 2; ++ks)
#pragma unroll
      for (int fm = 0; fm < 2; ++fm)
#pragma unroll
        for (int fn = 0; fn < 4; ++fn)
          acc[fm][fn] = __builtin_amdgcn_mfma_f32_16x16x32_bf16(
              afr[ks][fm], bfr[ks][fn], acc[fm][fn], 0, 0, 0);
  }
  int ldo = 4 * N;
#pragma unroll
  for (int fm = 0; fm < 2; ++fm) {
#pragma unroll
    for (int fn = 0; fn < 4; ++fn) {
      int colb = bn + fn * 16 + (lane & 15);
      if (colb >= N) continue;
      float bv = bias[h * N + colb];
#pragma unroll
      for (int j = 0; j < 4; ++j) {
        int rowb = bm + w * 32 + fm * 16 + (lane >> 4) * 4 + j;
        if (rowb >= M) continue;
        float v = acc[fm][fn][j] + bv;
        if (ACT) v = v > 0.f ? v : expm1f(v);
        size_t off = (size_t)rowb * ldo + (size_t)h * N + colb;
        if (OUTBF) ((unsigned short*)outv)[off] = f2b(v);
        else ((float*)outv)[off] = v;
      }
    }
  }
}

// mean over 4 heads (C=47) + log_softmax; one wave per node
__global__ __launch_bounds__(256) void k_mean_lsm(const float* __restrict__ rst2,
                                                  float* __restrict__ out, int Nd) {
  int node = blockIdx.x * 4 + (threadIdx.x >> 6);
  int lane = threadIdx.x & 63;
  if (node >= Nd) return;
  const float* r = rst2 + (size_t)node * 188;
  float vv = 0.f;
  if (lane < 47)
    vv = 0.25f * (r[lane] + r[47 + lane] + r[94 + lane] + r[141 + lane]);
  float m = (lane < 47) ? vv : -INFINITY;
  for (int off = 32; off > 0; off >>= 1) m = fmaxf(m, __shfl_xor(m, off));
  float ex = (lane < 47) ? __expf(vv - m) : 0.f;
  float ss = ex;
  for (int off = 32; off > 0; off >>= 1) ss += __shfl_xor(ss, off);
  if (lane < 47) out[(size_t)node * 47 + lane] = vv - m - logf(ss);
}

extern "C" void kernel_launch(void* const* d_in, const int* in_sizes, int n_in,
                              void* d_out, int out_size, void* d_ws, size_t ws_size,
                              hipStream_t stream) {
  (void)in_sizes; (void)n_in; (void)out_size; (void)ws_size;
  const float* x = (const float*)d_in[0];
  const int* srcs[3] = {(const int*)d_in[1], (const int*)d_in[3], (const int*)d_in[5]};
  const int* dsts[3] = {(const int*)d_in[2], (const int*)d_in[4], (const int*)d_in[6]};
  const float* Wsrc[3] = {(const float*)d_in[7], (const float*)d_in[12], (const float*)d_in[17]};
  const float* Wdst[3] = {(const float*)d_in[8], (const float*)d_in[13], (const float*)d_in[18]};
  const float* al[3]   = {(const float*)d_in[9], (const float*)d_in[14], (const float*)d_in[19]};
  const float* ar[3]   = {(const float*)d_in[10], (const float*)d_in[15], (const float*)d_in[20]};
  const float* bb[3]   = {(const float*)d_in[11], (const float*)d_in[16], (const float*)d_in[21]};

  char* p = (char*)d_ws;
  auto alloc = [&](size_t bytes) -> void* {
    void* r = (void*)p;
    p += (bytes + 255) & ~(size_t)255;
    return r;
  };
  unsigned short* xbf = (unsigned short*)alloc((size_t)150000 * 256 * 2);
  unsigned short* zbf = (unsigned short*)alloc((size_t)25000 * 1024 * 2);
  unsigned short* h1  = (unsigned short*)alloc((size_t)25000 * 512 * 2);
  unsigned short* h2  = (unsigned short*)alloc((size_t)6000 * 512 * 2);
  float* rst2   = (float*)alloc((size_t)1024 * 188 * 4);
  unsigned short* Wb0 = (unsigned short*)alloc((size_t)512 * 256 * 2);
  unsigned short* Wb1 = (unsigned short*)alloc((size_t)512 * 512 * 2);
  unsigned short* Wb2 = (unsigned short*)alloc((size_t)188 * 512 * 2);
  float* ell    = (float*)alloc((size_t)150000 * 4 * 4);
  float* err    = (float*)alloc((size_t)25000 * 4 * 4);
  int* cntAll   = (int*)alloc((size_t)(25000 + 6000 + 1024) * 4);
  int* rp0      = (int*)alloc((size_t)25001 * 4);
  int* rp1      = (int*)alloc((size_t)6001 * 4);
  int* rp2      = (int*)alloc((size_t)1025 * 4);
  int* r_all    = (int*)alloc((size_t)ETOT * 4);
  int* cv0      = (int*)alloc((size_t)E0 * 4);
  int* cv1      = (int*)alloc((size_t)E1 * 4);
  int* cv2      = (int*)alloc((size_t)E2 * 4);
  float* wlr    = (float*)alloc((size_t)8 * 512 * 4);

  int* cnt0 = cntAll, *cnt1 = cntAll + 25000, *cnt2 = cntAll + 31000;

  // ---- CSR build for all layers (topology only, hoisted out of layer loop)
  hipMemsetAsync(cntAll, 0, (size_t)(25000 + 6000 + 1024) * 4, stream);
  k_count_all<<<(ETOT + 255) / 256, 256, 0, stream>>>(
      dsts[0], dsts[1], dsts[2], cnt0, cnt1, cnt2, r_all);
  k_scan3<<<3, 1024, 0, stream>>>(cnt0, rp0, 25000, cnt1, rp1, 6000, cnt2, rp2, 1024);
  k_scatter_all<<<(ETOT + 255) / 256, 256, 0, stream>>>(
      srcs[0], dsts[0], rp0, cv0, srcs[1], dsts[1], rp1, cv1,
      srcs[2], dsts[2], rp2, cv2, r_all);

  // ---- weight conversions
  k_cvt_bf<<<(512 * 256 + 255) / 256, 256, 0, stream>>>(Wsrc[0], Wb0, 512 * 256);
  k_cvt_bf<<<(512 * 512 + 255) / 256, 256, 0, stream>>>(Wsrc[1], Wb1, 512 * 512);
  k_cvt_bf<<<(188 * 512 + 255) / 256, 256, 0, stream>>>(Wsrc[2], Wb2, 188 * 512);

  const unsigned short* Hbf[3] = {xbf, h1, h2};
  const unsigned short* Wbf[3] = {Wb0, Wb1, Wb2};
  const int* rps[3] = {rp0, rp1, rp2};
  const int* cvs[3] = {cv0, cv1, cv2};

  for (int l = 0; l < 3; ++l) {
    int Ns = L_NS[l], Nd = L_ND[l], Fin = L_FIN[l], Fout = L_FOUT[l];
    k_build_wlr<<<(8 * Fin + 255) / 256, 256, 0, stream>>>(
        Wsrc[l], Wdst[l], al[l], ar[l], wlr, Fin, Fout);
    if (l == 0)
      k_dot_cvt<<<(Ns + 3) / 4, 256, 0, stream>>>(x, wlr, xbf, ell, err, Ns, Nd);
    else
      k_dot_bf<<<(Ns + 3) / 4, 256, 0, stream>>>(Hbf[l], wlr, ell, err, Ns, Nd);
    if (Fin == 256)
      k_gather_fused<256><<<Nd, 64, 0, stream>>>(Hbf[l], ell, err, rps[l], cvs[l], zbf);
    else
      k_gather_fused<512><<<Nd, 128, 0, stream>>>(Hbf[l], ell, err, rps[l], cvs[l], zbf);
    dim3 g((Nd + 127) / 128, (Fout + 63) / 64, 4);
    if (l == 0)
      k_gemm_mfma<true, true><<<g, 256, 0, stream>>>(zbf, Wbf[l], bb[l], h1, Nd, Fout, Fin);
    else if (l == 1)
      k_gemm_mfma<true, true><<<g, 256, 0, stream>>>(zbf, Wbf[l], bb[l], h2, Nd, Fout, Fin);
    else
      k_gemm_mfma<false, false><<<g, 256, 0, stream>>>(zbf, Wbf[l], bb[l], rst2, Nd, Fout, Fin);
  }
  k_mean_lsm<<<(1024 + 3) / 4, 256, 0, stream>>>(rst2, (float*)d_out, 1024);
}

// Round 4
// 381.851 us; speedup vs baseline: 2.3379x; 1.1898x over previous
//
#include <hip/hip_runtime.h>
#include <math.h>

// ---------------------------------------------------------------------------
// GAT 3-layer pipeline. bf16 features + MFMA GEMMs, fused CSR edge-softmax.
//   el = h @ wl.T, wl[h,:] = al[h,:] @ Wsrc_h   (no fs materialization)
//   agg = (softmax-weighted sum of raw feats) @ Wsrc_h.T  (aggregate first)
// CSR built once upfront; per-dst gather computes max/exp/sum in-block.
// Dot kernels use a 27-op cross-lane reduction (butterfly/select/butterfly).
// ---------------------------------------------------------------------------

#define E0 375000
#define E1 90000
#define E2 10240
#define ETOT (E0 + E1 + E2)

static const int L_NS[3]   = {150000, 25000, 6000};
static const int L_ND[3]   = {25000, 6000, 1024};
static const int L_FIN[3]  = {256, 512, 512};
static const int L_FOUT[3] = {128, 128, 47};

typedef short bf8_t __attribute__((ext_vector_type(8)));
typedef float f32x4 __attribute__((ext_vector_type(4)));

__device__ __forceinline__ float lrelu(float v) { return v >= 0.f ? v : 0.2f * v; }
__device__ __forceinline__ unsigned short f2b(float f) {
  unsigned u = __float_as_uint(f);
  unsigned r = u + 0x7fffu + ((u >> 16) & 1u);
  return (unsigned short)(r >> 16);
}
__device__ __forceinline__ float b2f(unsigned v) {  // low 16 bits
  return __uint_as_float(v << 16);
}

// 8-value cross-lane sum: butterfly{8,16,32} x8, select v[lane>>3], butterfly{1,2,4}.
// Lanes 8h..8h+7 end with the full sum for output h; lane 8h stores it.
__device__ __forceinline__ void reduce8_store(float v[8], int lane, int node, int Nd,
                                              float* __restrict__ ell,
                                              float* __restrict__ err) {
#pragma unroll
  for (int h = 0; h < 8; ++h) {
    v[h] += __shfl_xor(v[h], 8);
    v[h] += __shfl_xor(v[h], 16);
    v[h] += __shfl_xor(v[h], 32);
  }
  int sel = lane >> 3;
  float t01 = (sel & 1) ? v[1] : v[0];
  float t23 = (sel & 1) ? v[3] : v[2];
  float t45 = (sel & 1) ? v[5] : v[4];
  float t67 = (sel & 1) ? v[7] : v[6];
  float t03 = (sel & 2) ? t23 : t01;
  float t47 = (sel & 2) ? t67 : t45;
  float s   = (sel & 4) ? t47 : t03;
  s += __shfl_xor(s, 1);
  s += __shfl_xor(s, 2);
  s += __shfl_xor(s, 4);
  if ((lane & 7) == 0) {
    if (sel < 4) ell[(size_t)node * 4 + sel] = s;
    else if (node < Nd) err[(size_t)node * 4 + (sel - 4)] = s;
  }
}

// ---------------- prologue (one-shot, topology/weights only) ----------------

// all 3 layers' wl/wr in one launch. wlrX: [0,4*Fin)=wl, [4*Fin,8*Fin)=wr.
__global__ void k_build_wlr_all(
    const float* __restrict__ Ws0, const float* __restrict__ Wd0,
    const float* __restrict__ al0, const float* __restrict__ ar0,
    const float* __restrict__ Ws1, const float* __restrict__ Wd1,
    const float* __restrict__ al1, const float* __restrict__ ar1,
    const float* __restrict__ Ws2, const float* __restrict__ Wd2,
    const float* __restrict__ al2, const float* __restrict__ ar2,
    float* __restrict__ wlr0, float* __restrict__ wlr1, float* __restrict__ wlr2) {
  int idx = blockIdx.x * 256 + threadIdx.x;
  const float *Ws, *Wd, *al, *ar; float* wlr; int Fin, Fout;
  if (idx < 2048) { Ws = Ws0; Wd = Wd0; al = al0; ar = ar0; wlr = wlr0; Fin = 256; Fout = 128; }
  else if (idx < 2048 + 4096) { idx -= 2048; Ws = Ws1; Wd = Wd1; al = al1; ar = ar1; wlr = wlr1; Fin = 512; Fout = 128; }
  else if (idx < 2048 + 8192) { idx -= 2048 + 4096; Ws = Ws2; Wd = Wd2; al = al2; ar = ar2; wlr = wlr2; Fin = 512; Fout = 47; }
  else return;
  int which = idx / (4 * Fin);
  int rem = idx - which * 4 * Fin;
  int h = rem / Fin, k = rem - h * Fin;
  const float* W = which ? Wd : Ws;
  const float* a = which ? ar : al;
  float acc = 0.f;
  for (int d = 0; d < Fout; ++d)
    acc += a[h * Fout + d] * W[(size_t)(h * Fout + d) * Fin + k];
  wlr[idx] = acc;
}

// all 3 weight matrices -> bf16, grid-stride
__global__ void k_cvt_all(const float* __restrict__ W0, const float* __restrict__ W1,
                          const float* __restrict__ W2, unsigned short* __restrict__ B0,
                          unsigned short* __restrict__ B1, unsigned short* __restrict__ B2) {
  const int n0 = 512 * 256, n1 = 512 * 512, n2 = 188 * 512;
  for (int i = blockIdx.x * 256 + threadIdx.x; i < n0 + n1 + n2; i += gridDim.x * 256) {
    if (i < n0) B0[i] = f2b(W0[i]);
    else if (i < n0 + n1) B1[i - n0] = f2b(W1[i - n0]);
    else B2[i - n0 - n1] = f2b(W2[i - n0 - n1]);
  }
}

__global__ void k_count_all(const int* __restrict__ d0, const int* __restrict__ d1,
                            const int* __restrict__ d2, int* __restrict__ c0,
                            int* __restrict__ c1, int* __restrict__ c2,
                            int* __restrict__ r) {
  int g = blockIdx.x * 256 + threadIdx.x;
  if (g >= ETOT) return;
  const int* d; int* c; int e;
  if (g < E0) { e = g; d = d0; c = c0; }
  else if (g < E0 + E1) { e = g - E0; d = d1; c = c1; }
  else { e = g - E0 - E1; d = d2; c = c2; }
  r[g] = atomicAdd(&c[d[e]], 1);
}

__global__ __launch_bounds__(1024) void k_scan3(
    const int* __restrict__ c0, int* __restrict__ r0, int n0,
    const int* __restrict__ c1, int* __restrict__ r1, int n1,
    const int* __restrict__ c2, int* __restrict__ r2, int n2) {
  const int* cnt; int* rowptr; int Nd;
  if (blockIdx.x == 0) { cnt = c0; rowptr = r0; Nd = n0; }
  else if (blockIdx.x == 1) { cnt = c1; rowptr = r1; Nd = n1; }
  else { cnt = c2; rowptr = r2; Nd = n2; }
  __shared__ int wsum[16];
  __shared__ int carry_s;
  int t = threadIdx.x, wid = t >> 6, lane = t & 63;
  if (t == 0) { carry_s = 0; rowptr[0] = 0; }
  __syncthreads();
  for (int base = 0; base < Nd; base += 4096) {
    int i0 = base + t * 4;
    int v0 = (i0 + 0 < Nd) ? cnt[i0 + 0] : 0;
    int v1 = (i0 + 1 < Nd) ? cnt[i0 + 1] : 0;
    int v2 = (i0 + 2 < Nd) ? cnt[i0 + 2] : 0;
    int v3 = (i0 + 3 < Nd) ? cnt[i0 + 3] : 0;
    int ts = v0 + v1 + v2 + v3;
    int s = ts;
    for (int off = 1; off < 64; off <<= 1) {
      int u = __shfl_up(s, off);
      if (lane >= off) s += u;
    }
    if (lane == 63) wsum[wid] = s;
    __syncthreads();
    int woff = carry_s;
    for (int w2 = 0; w2 < wid; ++w2) woff += wsum[w2];
    int excl = woff + s - ts;
    int p0 = excl + v0, p1 = p0 + v1, p2 = p1 + v2, p3 = p2 + v3;
    if (i0 + 0 < Nd) rowptr[i0 + 1] = p0;
    if (i0 + 1 < Nd) rowptr[i0 + 2] = p1;
    if (i0 + 2 < Nd) rowptr[i0 + 3] = p2;
    if (i0 + 3 < Nd) rowptr[i0 + 4] = p3;
    __syncthreads();
    if (t == 1023) carry_s = p3;
  }
}

__global__ void k_scatter_all(
    const int* __restrict__ s0, const int* __restrict__ d0, const int* __restrict__ rp0, int* __restrict__ cv0,
    const int* __restrict__ s1, const int* __restrict__ d1, const int* __restrict__ rp1, int* __restrict__ cv1,
    const int* __restrict__ s2, const int* __restrict__ d2, const int* __restrict__ rp2, int* __restrict__ cv2,
    const int* __restrict__ r) {
  int g = blockIdx.x * 256 + threadIdx.x;
  if (g >= ETOT) return;
  const int* s; const int* d; const int* rp; int* cv; int e;
  if (g < E0) { e = g; s = s0; d = d0; rp = rp0; cv = cv0; }
  else if (g < E0 + E1) { e = g - E0; s = s1; d = d1; rp = rp1; cv = cv1; }
  else { e = g - E0 - E1; s = s2; d = d2; rp = rp2; cv = cv2; }
  cv[rp[d[e]] + r[g]] = s[e];
}

// ---------------- per-layer feature kernels ----------------

// layer 0: fp32 x -> ell/err + bf16 copy. Fin=256, one wave per node.
__global__ __launch_bounds__(256) void k_dot_cvt(
    const float* __restrict__ x, const float* __restrict__ wlr,
    unsigned short* __restrict__ xbf, float* __restrict__ ell, float* __restrict__ err,
    int Ns, int Nd) {
  int node = blockIdx.x * 4 + (threadIdx.x >> 6);
  int lane = threadIdx.x & 63;
  if (node >= Ns) return;
  float4 xv = *reinterpret_cast<const float4*>(x + (size_t)node * 256 + lane * 4);
  ushort4 ub;
  ub.x = f2b(xv.x); ub.y = f2b(xv.y); ub.z = f2b(xv.z); ub.w = f2b(xv.w);
  *reinterpret_cast<ushort4*>(xbf + (size_t)node * 256 + lane * 4) = ub;
  bool nR = node < Nd;
  float v[8];
#pragma unroll
  for (int h = 0; h < 4; ++h) {
    float4 wv = *reinterpret_cast<const float4*>(wlr + h * 256 + lane * 4);
    v[h] = xv.x * wv.x + xv.y * wv.y + xv.z * wv.z + xv.w * wv.w;
    v[4 + h] = 0.f;
    if (nR) {
      float4 w2 = *reinterpret_cast<const float4*>(wlr + 1024 + h * 256 + lane * 4);
      v[4 + h] = xv.x * w2.x + xv.y * w2.y + xv.z * w2.z + xv.w * w2.w;
    }
  }
  reduce8_store(v, lane, node, Nd, ell, err);
}

// layers 1/2: bf16 features, Fin=512, one wave per node.
__global__ __launch_bounds__(256) void k_dot_bf(
    const unsigned short* __restrict__ Hs, const float* __restrict__ wlr,
    float* __restrict__ ell, float* __restrict__ err, int Ns, int Nd) {
  int node = blockIdx.x * 4 + (threadIdx.x >> 6);
  int lane = threadIdx.x & 63;
  if (node >= Ns) return;
  uint4 raw = *reinterpret_cast<const uint4*>(Hs + (size_t)node * 512 + lane * 8);
  float xv[8];
  xv[0] = b2f(raw.x & 0xffffu); xv[1] = b2f(raw.x >> 16);
  xv[2] = b2f(raw.y & 0xffffu); xv[3] = b2f(raw.y >> 16);
  xv[4] = b2f(raw.z & 0xffffu); xv[5] = b2f(raw.z >> 16);
  xv[6] = b2f(raw.w & 0xffffu); xv[7] = b2f(raw.w >> 16);
  bool nR = node < Nd;
  float v[8];
#pragma unroll
  for (int h = 0; h < 4; ++h) {
    const float* wp = wlr + h * 512 + lane * 8;
    float4 w0 = *reinterpret_cast<const float4*>(wp);
    float4 w1 = *reinterpret_cast<const float4*>(wp + 4);
    v[h] = xv[0]*w0.x + xv[1]*w0.y + xv[2]*w0.z + xv[3]*w0.w +
           xv[4]*w1.x + xv[5]*w1.y + xv[6]*w1.z + xv[7]*w1.w;
    v[4 + h] = 0.f;
    if (nR) {
      const float* wq = wlr + 2048 + h * 512 + lane * 8;
      float4 u0 = *reinterpret_cast<const float4*>(wq);
      float4 u1 = *reinterpret_cast<const float4*>(wq + 4);
      v[4 + h] = xv[0]*u0.x + xv[1]*u0.y + xv[2]*u0.z + xv[3]*u0.w +
                 xv[4]*u1.x + xv[5]*u1.y + xv[6]*u1.z + xv[7]*u1.w;
    }
  }
  reduce8_store(v, lane, node, Nd, ell, err);
}

// fused per-dst softmax + weighted bf16 feature gather (block = one dst node).
template <int FIN>
__global__ __launch_bounds__(FIN / 4) void k_gather_fused(
    const unsigned short* __restrict__ Hs, const float* __restrict__ ell,
    const float* __restrict__ err, const int* __restrict__ rowptr,
    const int* __restrict__ colv, unsigned short* __restrict__ Z) {
  constexpr int TB = FIN / 4;
  constexpr int NW = TB / 64;
  constexpr int CAP = 256;
  int n = blockIdx.x, t = threadIdx.x;
  int beg = rowptr[n], cnt = rowptr[n + 1] - beg;
  float4 er4 = *reinterpret_cast<const float4*>(err + (size_t)n * 4);
  __shared__ float4 esm[CAP];
  __shared__ int csm[CAP];
  __shared__ float4 wred[NW > 1 ? NW : 1];
  float m0 = -INFINITY, m1 = -INFINITY, m2 = -INFINITY, m3 = -INFINITY;
  for (int i = t; i < cnt; i += TB) {
    int c = colv[beg + i];
    float4 el4 = *reinterpret_cast<const float4*>(ell + (size_t)c * 4);
    float4 e4;
    e4.x = lrelu(el4.x + er4.x); e4.y = lrelu(el4.y + er4.y);
    e4.z = lrelu(el4.z + er4.z); e4.w = lrelu(el4.w + er4.w);
    if (i < CAP) { csm[i] = c; esm[i] = e4; }
    m0 = fmaxf(m0, e4.x); m1 = fmaxf(m1, e4.y);
    m2 = fmaxf(m2, e4.z); m3 = fmaxf(m3, e4.w);
  }
  for (int off = 32; off > 0; off >>= 1) {
    m0 = fmaxf(m0, __shfl_xor(m0, off));
    m1 = fmaxf(m1, __shfl_xor(m1, off));
    m2 = fmaxf(m2, __shfl_xor(m2, off));
    m3 = fmaxf(m3, __shfl_xor(m3, off));
  }
  if constexpr (NW > 1) {
    if ((t & 63) == 0) wred[t >> 6] = make_float4(m0, m1, m2, m3);
  }
  __syncthreads();  // esm/csm (+wred) visible
  if constexpr (NW > 1) {
    float4 wa = wred[0], wb = wred[1];
    m0 = fmaxf(wa.x, wb.x); m1 = fmaxf(wa.y, wb.y);
    m2 = fmaxf(wa.z, wb.z); m3 = fmaxf(wa.w, wb.w);
  }
  float s0 = 0.f, s1 = 0.f, s2 = 0.f, s3 = 0.f;
  float acc[4][4] = {};

#define GAT_ACC(e4, xr)                                                        \
  {                                                                            \
    float w0 = __expf(e4.x - m0), w1 = __expf(e4.y - m1);                      \
    float w2 = __expf(e4.z - m2), w3 = __expf(e4.w - m3);                      \
    s0 += w0; s1 += w1; s2 += w2; s3 += w3;                                    \
    float x0 = b2f(xr.x), x1 = b2f(xr.y), x2 = b2f(xr.z), x3 = b2f(xr.w);      \
    acc[0][0] = fmaf(w0, x0, acc[0][0]); acc[0][1] = fmaf(w0, x1, acc[0][1]);  \
    acc[0][2] = fmaf(w0, x2, acc[0][2]); acc[0][3] = fmaf(w0, x3, acc[0][3]);  \
    acc[1][0] = fmaf(w1, x0, acc[1][0]); acc[1][1] = fmaf(w1, x1, acc[1][1]);  \
    acc[1][2] = fmaf(w1, x2, acc[1][2]); acc[1][3] = fmaf(w1, x3, acc[1][3]);  \
    acc[2][0] = fmaf(w2, x0, acc[2][0]); acc[2][1] = fmaf(w2, x1, acc[2][1]);  \
    acc[2][2] = fmaf(w2, x2, acc[2][2]); acc[2][3] = fmaf(w2, x3, acc[2][3]);  \
    acc[3][0] = fmaf(w3, x0, acc[3][0]); acc[3][1] = fmaf(w3, x1, acc[3][1]);  \
    acc[3][2] = fmaf(w3, x2, acc[3][2]); acc[3][3] = fmaf(w3, x3, acc[3][3]);  \
  }

  if (cnt <= CAP) {
    int j = 0;
    for (; j + 2 <= cnt; j += 2) {
      float4 ea = esm[j], eb = esm[j + 1];
      int ca = csm[j], cb = csm[j + 1];
      ushort4 xa = *reinterpret_cast<const ushort4*>(Hs + (size_t)ca * FIN + t * 4);
      ushort4 xb = *reinterpret_cast<const ushort4*>(Hs + (size_t)cb * FIN + t * 4);
      GAT_ACC(ea, xa);
      GAT_ACC(eb, xb);
    }
    if (j < cnt) {
      float4 ea = esm[j];
      ushort4 xa = *reinterpret_cast<const ushort4*>(Hs + (size_t)csm[j] * FIN + t * 4);
      GAT_ACC(ea, xa);
    }
  } else {
    for (int j = 0; j < cnt; ++j) {
      int c = colv[beg + j];
      float4 el4 = *reinterpret_cast<const float4*>(ell + (size_t)c * 4);
      float4 e4;
      e4.x = lrelu(el4.x + er4.x); e4.y = lrelu(el4.y + er4.y);
      e4.z = lrelu(el4.z + er4.z); e4.w = lrelu(el4.w + er4.w);
      ushort4 xa = *reinterpret_cast<const ushort4*>(Hs + (size_t)c * FIN + t * 4);
      GAT_ACC(e4, xa);
    }
  }
#undef GAT_ACC
  float inv[4];
  inv[0] = 1.f / fmaxf(s0, 1e-9f); inv[1] = 1.f / fmaxf(s1, 1e-9f);
  inv[2] = 1.f / fmaxf(s2, 1e-9f); inv[3] = 1.f / fmaxf(s3, 1e-9f);
#pragma unroll
  for (int h = 0; h < 4; ++h) {
    ushort4 o;
    o.x = f2b(acc[h][0] * inv[h]); o.y = f2b(acc[h][1] * inv[h]);
    o.z = f2b(acc[h][2] * inv[h]); o.w = f2b(acc[h][3] * inv[h]);
    *reinterpret_cast<ushort4*>(Z + (size_t)n * 4 * FIN + h * FIN + t * 4) = o;
  }
}

// bf16 MFMA GEMM, per-head: out[m, h*N+n] = (Z_h @ W_h^T)[m,n] + bias  (opt ELU)
// 128xBN tile, BK=64, 256 thr (4 waves, each 32 rows x BN cols), 16x16x32 MFMA.
template <int BN, bool ACT, bool OUTBF>
__global__ __launch_bounds__(256) void k_gemm_mfma(
    const unsigned short* __restrict__ Zb, const unsigned short* __restrict__ Wb,
    const float* __restrict__ bias, void* __restrict__ outv,
    int M, int N, int K) {
  constexpr int FN = BN / 16;
  int h = blockIdx.z;
  __shared__ unsigned short As[128][72];
  __shared__ unsigned short Bs[BN][72];
  int tid = threadIdx.x;
  int bm = blockIdx.x * 128, bn = blockIdx.y * BN;
  int lda = 4 * K;
  const unsigned short* Ag = Zb + (size_t)h * K;
  const unsigned short* Bg = Wb + (size_t)h * N * K;
  int ar = tid >> 3, aseg = tid & 7;
  int w = tid >> 6, lane = tid & 63;
  f32x4 acc[2][FN] = {};
  for (int k0 = 0; k0 < K; k0 += 64) {
    __syncthreads();
#pragma unroll
    for (int i = 0; i < 4; ++i) {
      int r = ar + i * 32;
      int gm = bm + r;
      uint4 v = make_uint4(0u, 0u, 0u, 0u);
      if (gm < M) v = *reinterpret_cast<const uint4*>(Ag + (size_t)gm * lda + k0 + aseg * 8);
      *reinterpret_cast<uint4*>(&As[r][aseg * 8]) = v;
    }
#pragma unroll
    for (int i = 0; i < BN / 32; ++i) {
      int r = ar + i * 32;
      int gn = bn + r;
      uint4 v = make_uint4(0u, 0u, 0u, 0u);
      if (gn < N) v = *reinterpret_cast<const uint4*>(Bg + (size_t)gn * K + k0 + aseg * 8);
      *reinterpret_cast<uint4*>(&Bs[r][aseg * 8]) = v;
    }
    __syncthreads();
    int row0 = w * 32;
#pragma unroll
    for (int ks = 0; ks < 2; ++ks) {
      bf8_t a0 = *reinterpret_cast<const bf8_t*>(
          &As[row0 + (lane & 15)][ks * 32 + (lane >> 4) * 8]);
      bf8_t a1 = *reinterpret_cast<const bf8_t*>(
          &As[row0 + 16 + (lane & 15)][ks * 32 + (lane >> 4) * 8]);
#pragma unroll
      for (int fn = 0; fn < FN; ++fn) {
        bf8_t bf = *reinterpret_cast<const bf8_t*>(
            &Bs[fn * 16 + (lane & 15)][ks * 32 + (lane >> 4) * 8]);
        acc[0][fn] = __builtin_amdgcn_mfma_f32_16x16x32_bf16(a0, bf, acc[0][fn], 0, 0, 0);
        acc[1][fn] = __builtin_amdgcn_mfma_f32_16x16x32_bf16(a1, bf, acc[1][fn], 0, 0, 0);
      }
    }
  }
  int ldo = 4 * N;
#pragma unroll
  for (int fm = 0; fm < 2; ++fm) {
#pragma unroll
    for (int fn = 0; fn < FN; ++fn) {
      int colb = bn + fn * 16 + (lane & 15);
      if (colb >= N) continue;
      float bv = bias[h * N + colb];
#pragma unroll
      for (int j = 0; j < 4; ++j) {
        int rowb = bm + w * 32 + fm * 16 + (lane >> 4) * 4 + j;
        if (rowb >= M) continue;
        float v = acc[fm][fn][j] + bv;
        if (ACT) v = v > 0.f ? v : expm1f(v);
        size_t off = (size_t)rowb * ldo + (size_t)h * N + colb;
        if (OUTBF) ((unsigned short*)outv)[off] = f2b(v);
        else ((float*)outv)[off] = v;
      }
    }
  }
}

// mean over 4 heads (C=47) + log_softmax; one wave per node
__global__ __launch_bounds__(256) void k_mean_lsm(const float* __restrict__ rst2,
                                                  float* __restrict__ out, int Nd) {
  int node = blockIdx.x * 4 + (threadIdx.x >> 6);
  int lane = threadIdx.x & 63;
  if (node >= Nd) return;
  const float* r = rst2 + (size_t)node * 188;
  float vv = 0.f;
  if (lane < 47)
    vv = 0.25f * (r[lane] + r[47 + lane] + r[94 + lane] + r[141 + lane]);
  float m = (lane < 47) ? vv : -INFINITY;
  for (int off = 32; off > 0; off >>= 1) m = fmaxf(m, __shfl_xor(m, off));
  float ex = (lane < 47) ? __expf(vv - m) : 0.f;
  float ss = ex;
  for (int off = 32; off > 0; off >>= 1) ss += __shfl_xor(ss, off);
  if (lane < 47) out[(size_t)node * 47 + lane] = vv - m - logf(ss);
}

extern "C" void kernel_launch(void* const* d_in, const int* in_sizes, int n_in,
                              void* d_out, int out_size, void* d_ws, size_t ws_size,
                              hipStream_t stream) {
  (void)in_sizes; (void)n_in; (void)out_size; (void)ws_size;
  const float* x = (const float*)d_in[0];
  const int* srcs[3] = {(const int*)d_in[1], (const int*)d_in[3], (const int*)d_in[5]};
  const int* dsts[3] = {(const int*)d_in[2], (const int*)d_in[4], (const int*)d_in[6]};
  const float* Wsrc[3] = {(const float*)d_in[7], (const float*)d_in[12], (const float*)d_in[17]};
  const float* Wdst[3] = {(const float*)d_in[8], (const float*)d_in[13], (const float*)d_in[18]};
  const float* al[3]   = {(const float*)d_in[9], (const float*)d_in[14], (const float*)d_in[19]};
  const float* ar[3]   = {(const float*)d_in[10], (const float*)d_in[15], (const float*)d_in[20]};
  const float* bb[3]   = {(const float*)d_in[11], (const float*)d_in[16], (const float*)d_in[21]};

  char* p = (char*)d_ws;
  auto alloc = [&](size_t bytes) -> void* {
    void* r = (void*)p;
    p += (bytes + 255) & ~(size_t)255;
    return r;
  };
  unsigned short* xbf = (unsigned short*)alloc((size_t)150000 * 256 * 2);
  unsigned short* zbf = (unsigned short*)alloc((size_t)25000 * 1024 * 2);
  unsigned short* h1  = (unsigned short*)alloc((size_t)25000 * 512 * 2);
  unsigned short* h2  = (unsigned short*)alloc((size_t)6000 * 512 * 2);
  float* rst2   = (float*)alloc((size_t)1024 * 188 * 4);
  unsigned short* Wb0 = (unsigned short*)alloc((size_t)512 * 256 * 2);
  unsigned short* Wb1 = (unsigned short*)alloc((size_t)512 * 512 * 2);
  unsigned short* Wb2 = (unsigned short*)alloc((size_t)188 * 512 * 2);
  float* ell    = (float*)alloc((size_t)150000 * 4 * 4);
  float* err    = (float*)alloc((size_t)25000 * 4 * 4);
  int* cntAll   = (int*)alloc((size_t)(25000 + 6000 + 1024) * 4);
  int* rp0      = (int*)alloc((size_t)25001 * 4);
  int* rp1      = (int*)alloc((size_t)6001 * 4);
  int* rp2      = (int*)alloc((size_t)1025 * 4);
  int* r_all    = (int*)alloc((size_t)ETOT * 4);
  int* cv0      = (int*)alloc((size_t)E0 * 4);
  int* cv1      = (int*)alloc((size_t)E1 * 4);
  int* cv2      = (int*)alloc((size_t)E2 * 4);
  float* wlr0   = (float*)alloc((size_t)8 * 256 * 4);
  float* wlr1   = (float*)alloc((size_t)8 * 512 * 4);
  float* wlr2   = (float*)alloc((size_t)8 * 512 * 4);

  int* cnt0 = cntAll, *cnt1 = cntAll + 25000, *cnt2 = cntAll + 31000;

  // ---- one-shot prologue: CSR + weight prep
  hipMemsetAsync(cntAll, 0, (size_t)(25000 + 6000 + 1024) * 4, stream);
  k_count_all<<<(ETOT + 255) / 256, 256, 0, stream>>>(
      dsts[0], dsts[1], dsts[2], cnt0, cnt1, cnt2, r_all);
  k_scan3<<<3, 1024, 0, stream>>>(cnt0, rp0, 25000, cnt1, rp1, 6000, cnt2, rp2, 1024);
  k_scatter_all<<<(ETOT + 255) / 256, 256, 0, stream>>>(
      srcs[0], dsts[0], rp0, cv0, srcs[1], dsts[1], rp1, cv1,
      srcs[2], dsts[2], rp2, cv2, r_all);
  k_build_wlr_all<<<(10240 + 255) / 256, 256, 0, stream>>>(
      Wsrc[0], Wdst[0], al[0], ar[0], Wsrc[1], Wdst[1], al[1], ar[1],
      Wsrc[2], Wdst[2], al[2], ar[2], wlr0, wlr1, wlr2);
  k_cvt_all<<<512, 256, 0, stream>>>(Wsrc[0], Wsrc[1], Wsrc[2], Wb0, Wb1, Wb2);

  const unsigned short* Hbf[3] = {xbf, h1, h2};
  const unsigned short* Wbf[3] = {Wb0, Wb1, Wb2};
  const float* wlrs[3] = {wlr0, wlr1, wlr2};
  const int* rps[3] = {rp0, rp1, rp2};
  const int* cvs[3] = {cv0, cv1, cv2};

  for (int l = 0; l < 3; ++l) {
    int Ns = L_NS[l], Nd = L_ND[l], Fin = L_FIN[l], Fout = L_FOUT[l];
    if (l == 0)
      k_dot_cvt<<<(Ns + 3) / 4, 256, 0, stream>>>(x, wlrs[l], xbf, ell, err, Ns, Nd);
    else
      k_dot_bf<<<(Ns + 3) / 4, 256, 0, stream>>>(Hbf[l], wlrs[l], ell, err, Ns, Nd);
    if (Fin == 256)
      k_gather_fused<256><<<Nd, 64, 0, stream>>>(Hbf[l], ell, err, rps[l], cvs[l], zbf);
    else
      k_gather_fused<512><<<Nd, 128, 0, stream>>>(Hbf[l], ell, err, rps[l], cvs[l], zbf);
    if (l == 0) {
      dim3 g((Nd + 127) / 128, 1, 4);
      k_gemm_mfma<128, true, true><<<g, 256, 0, stream>>>(zbf, Wbf[l], bb[l], h1, Nd, Fout, Fin);
    } else if (l == 1) {
      dim3 g((Nd + 127) / 128, 1, 4);
      k_gemm_mfma<128, true, true><<<g, 256, 0, stream>>>(zbf, Wbf[l], bb[l], h2, Nd, Fout, Fin);
    } else {
      dim3 g((Nd + 127) / 128, 1, 4);
      k_gemm_mfma<64, false, false><<<g, 256, 0, stream>>>(zbf, Wbf[l], bb[l], rst2, Nd, Fout, Fin);
    }
  }
  k_mean_lsm<<<(1024 + 3) / 4, 256, 0, stream>>>(rst2, (float*)d_out, 1024);
}

// Round 5
// 335.239 us; speedup vs baseline: 2.6629x; 1.1390x over previous
//
#include <hip/hip_runtime.h>
#include <math.h>

// ---------------------------------------------------------------------------
// GAT 3-layer pipeline. bf16 features + MFMA GEMMs, fused CSR edge-softmax.
//   el = h @ wl.T, wl[h,:] = al[h,:] @ Wsrc_h   (no fs materialization)
//   agg = (softmax-weighted sum of raw feats) @ Wsrc_h.T  (aggregate first)
// CSR built once upfront; per-dst gather computes max/exp/sum in-block.
// GEMM: global_load_lds(16B) staging into linear LDS with XOR seg-swizzle
// (swizzled global source + swizzled ds_read; LDS linear per gload_lds rules).
// ---------------------------------------------------------------------------

#define E0 375000
#define E1 90000
#define E2 10240
#define ETOT (E0 + E1 + E2)

static const int L_NS[3]   = {150000, 25000, 6000};
static const int L_ND[3]   = {25000, 6000, 1024};
static const int L_FIN[3]  = {256, 512, 512};
static const int L_FOUT[3] = {128, 128, 47};

typedef short bf8_t __attribute__((ext_vector_type(8)));
typedef float f32x4 __attribute__((ext_vector_type(4)));

__device__ __forceinline__ float lrelu(float v) { return v >= 0.f ? v : 0.2f * v; }
__device__ __forceinline__ unsigned short f2b(float f) {
  unsigned u = __float_as_uint(f);
  unsigned r = u + 0x7fffu + ((u >> 16) & 1u);
  return (unsigned short)(r >> 16);
}
__device__ __forceinline__ float b2f(unsigned v) {  // low 16 bits
  return __uint_as_float(v << 16);
}

// async global->LDS, 16B per lane; LDS dest = wave-uniform base + lane*16
__device__ __forceinline__ void gload16(const unsigned short* g, unsigned short* l) {
  __builtin_amdgcn_global_load_lds(
      (const __attribute__((address_space(1))) unsigned int*)g,
      (__attribute__((address_space(3))) unsigned int*)l, 16, 0, 0);
}

// 8-value cross-lane sum: butterfly{8,16,32} x8, select v[lane>>3], butterfly{1,2,4}.
__device__ __forceinline__ void reduce8_store(float v[8], int lane, int node, int Nd,
                                              float* __restrict__ ell,
                                              float* __restrict__ err) {
#pragma unroll
  for (int h = 0; h < 8; ++h) {
    v[h] += __shfl_xor(v[h], 8);
    v[h] += __shfl_xor(v[h], 16);
    v[h] += __shfl_xor(v[h], 32);
  }
  int sel = lane >> 3;
  float t01 = (sel & 1) ? v[1] : v[0];
  float t23 = (sel & 1) ? v[3] : v[2];
  float t45 = (sel & 1) ? v[5] : v[4];
  float t67 = (sel & 1) ? v[7] : v[6];
  float t03 = (sel & 2) ? t23 : t01;
  float t47 = (sel & 2) ? t67 : t45;
  float s   = (sel & 4) ? t47 : t03;
  s += __shfl_xor(s, 1);
  s += __shfl_xor(s, 2);
  s += __shfl_xor(s, 4);
  if ((lane & 7) == 0) {
    if (sel < 4) ell[(size_t)node * 4 + sel] = s;
    else if (node < Nd) err[(size_t)node * 4 + (sel - 4)] = s;
  }
}

// ---------------- prologue (one-shot, topology/weights only) ----------------

__global__ void k_build_wlr_all(
    const float* __restrict__ Ws0, const float* __restrict__ Wd0,
    const float* __restrict__ al0, const float* __restrict__ ar0,
    const float* __restrict__ Ws1, const float* __restrict__ Wd1,
    const float* __restrict__ al1, const float* __restrict__ ar1,
    const float* __restrict__ Ws2, const float* __restrict__ Wd2,
    const float* __restrict__ al2, const float* __restrict__ ar2,
    float* __restrict__ wlr0, float* __restrict__ wlr1, float* __restrict__ wlr2) {
  int idx = blockIdx.x * 256 + threadIdx.x;
  const float *Ws, *Wd, *al, *ar; float* wlr; int Fin, Fout;
  if (idx < 2048) { Ws = Ws0; Wd = Wd0; al = al0; ar = ar0; wlr = wlr0; Fin = 256; Fout = 128; }
  else if (idx < 2048 + 4096) { idx -= 2048; Ws = Ws1; Wd = Wd1; al = al1; ar = ar1; wlr = wlr1; Fin = 512; Fout = 128; }
  else if (idx < 2048 + 8192) { idx -= 2048 + 4096; Ws = Ws2; Wd = Wd2; al = al2; ar = ar2; wlr = wlr2; Fin = 512; Fout = 47; }
  else return;
  int which = idx / (4 * Fin);
  int rem = idx - which * 4 * Fin;
  int h = rem / Fin, k = rem - h * Fin;
  const float* W = which ? Wd : Ws;
  const float* a = which ? ar : al;
  float acc = 0.f;
  for (int d = 0; d < Fout; ++d)
    acc += a[h * Fout + d] * W[(size_t)(h * Fout + d) * Fin + k];
  wlr[idx] = acc;
}

__global__ void k_cvt_all(const float* __restrict__ W0, const float* __restrict__ W1,
                          const float* __restrict__ W2, unsigned short* __restrict__ B0,
                          unsigned short* __restrict__ B1, unsigned short* __restrict__ B2) {
  const int n0 = 512 * 256, n1 = 512 * 512, n2 = 188 * 512;
  for (int i = blockIdx.x * 256 + threadIdx.x; i < n0 + n1 + n2; i += gridDim.x * 256) {
    if (i < n0) B0[i] = f2b(W0[i]);
    else if (i < n0 + n1) B1[i - n0] = f2b(W1[i - n0]);
    else B2[i - n0 - n1] = f2b(W2[i - n0 - n1]);
  }
}

__global__ void k_count_all(const int* __restrict__ d0, const int* __restrict__ d1,
                            const int* __restrict__ d2, int* __restrict__ c0,
                            int* __restrict__ c1, int* __restrict__ c2,
                            int* __restrict__ r) {
  int g = blockIdx.x * 256 + threadIdx.x;
  if (g >= ETOT) return;
  const int* d; int* c; int e;
  if (g < E0) { e = g; d = d0; c = c0; }
  else if (g < E0 + E1) { e = g - E0; d = d1; c = c1; }
  else { e = g - E0 - E1; d = d2; c = c2; }
  r[g] = atomicAdd(&c[d[e]], 1);
}

__global__ __launch_bounds__(1024) void k_scan3(
    const int* __restrict__ c0, int* __restrict__ r0, int n0,
    const int* __restrict__ c1, int* __restrict__ r1, int n1,
    const int* __restrict__ c2, int* __restrict__ r2, int n2) {
  const int* cnt; int* rowptr; int Nd;
  if (blockIdx.x == 0) { cnt = c0; rowptr = r0; Nd = n0; }
  else if (blockIdx.x == 1) { cnt = c1; rowptr = r1; Nd = n1; }
  else { cnt = c2; rowptr = r2; Nd = n2; }
  __shared__ int wsum[16];
  __shared__ int carry_s;
  int t = threadIdx.x, wid = t >> 6, lane = t & 63;
  if (t == 0) { carry_s = 0; rowptr[0] = 0; }
  __syncthreads();
  for (int base = 0; base < Nd; base += 4096) {
    int i0 = base + t * 4;
    int v0 = (i0 + 0 < Nd) ? cnt[i0 + 0] : 0;
    int v1 = (i0 + 1 < Nd) ? cnt[i0 + 1] : 0;
    int v2 = (i0 + 2 < Nd) ? cnt[i0 + 2] : 0;
    int v3 = (i0 + 3 < Nd) ? cnt[i0 + 3] : 0;
    int ts = v0 + v1 + v2 + v3;
    int s = ts;
    for (int off = 1; off < 64; off <<= 1) {
      int u = __shfl_up(s, off);
      if (lane >= off) s += u;
    }
    if (lane == 63) wsum[wid] = s;
    __syncthreads();
    int woff = carry_s;
    for (int w2 = 0; w2 < wid; ++w2) woff += wsum[w2];
    int excl = woff + s - ts;
    int p0 = excl + v0, p1 = p0 + v1, p2 = p1 + v2, p3 = p2 + v3;
    if (i0 + 0 < Nd) rowptr[i0 + 1] = p0;
    if (i0 + 1 < Nd) rowptr[i0 + 2] = p1;
    if (i0 + 2 < Nd) rowptr[i0 + 3] = p2;
    if (i0 + 3 < Nd) rowptr[i0 + 4] = p3;
    __syncthreads();
    if (t == 1023) carry_s = p3;
  }
}

__global__ void k_scatter_all(
    const int* __restrict__ s0, const int* __restrict__ d0, const int* __restrict__ rp0, int* __restrict__ cv0,
    const int* __restrict__ s1, const int* __restrict__ d1, const int* __restrict__ rp1, int* __restrict__ cv1,
    const int* __restrict__ s2, const int* __restrict__ d2, const int* __restrict__ rp2, int* __restrict__ cv2,
    const int* __restrict__ r) {
  int g = blockIdx.x * 256 + threadIdx.x;
  if (g >= ETOT) return;
  const int* s; const int* d; const int* rp; int* cv; int e;
  if (g < E0) { e = g; s = s0; d = d0; rp = rp0; cv = cv0; }
  else if (g < E0 + E1) { e = g - E0; s = s1; d = d1; rp = rp1; cv = cv1; }
  else { e = g - E0 - E1; s = s2; d = d2; rp = rp2; cv = cv2; }
  cv[rp[d[e]] + r[g]] = s[e];
}

// ---------------- per-layer feature kernels ----------------

__global__ __launch_bounds__(256) void k_dot_cvt(
    const float* __restrict__ x, const float* __restrict__ wlr,
    unsigned short* __restrict__ xbf, float* __restrict__ ell, float* __restrict__ err,
    int Ns, int Nd) {
  int node = blockIdx.x * 4 + (threadIdx.x >> 6);
  int lane = threadIdx.x & 63;
  if (node >= Ns) return;
  float4 xv = *reinterpret_cast<const float4*>(x + (size_t)node * 256 + lane * 4);
  ushort4 ub;
  ub.x = f2b(xv.x); ub.y = f2b(xv.y); ub.z = f2b(xv.z); ub.w = f2b(xv.w);
  *reinterpret_cast<ushort4*>(xbf + (size_t)node * 256 + lane * 4) = ub;
  bool nR = node < Nd;
  float v[8];
#pragma unroll
  for (int h = 0; h < 4; ++h) {
    float4 wv = *reinterpret_cast<const float4*>(wlr + h * 256 + lane * 4);
    v[h] = xv.x * wv.x + xv.y * wv.y + xv.z * wv.z + xv.w * wv.w;
    v[4 + h] = 0.f;
    if (nR) {
      float4 w2 = *reinterpret_cast<const float4*>(wlr + 1024 + h * 256 + lane * 4);
      v[4 + h] = xv.x * w2.x + xv.y * w2.y + xv.z * w2.z + xv.w * w2.w;
    }
  }
  reduce8_store(v, lane, node, Nd, ell, err);
}

__global__ __launch_bounds__(256) void k_dot_bf(
    const unsigned short* __restrict__ Hs, const float* __restrict__ wlr,
    float* __restrict__ ell, float* __restrict__ err, int Ns, int Nd) {
  int node = blockIdx.x * 4 + (threadIdx.x >> 6);
  int lane = threadIdx.x & 63;
  if (node >= Ns) return;
  uint4 raw = *reinterpret_cast<const uint4*>(Hs + (size_t)node * 512 + lane * 8);
  float xv[8];
  xv[0] = b2f(raw.x & 0xffffu); xv[1] = b2f(raw.x >> 16);
  xv[2] = b2f(raw.y & 0xffffu); xv[3] = b2f(raw.y >> 16);
  xv[4] = b2f(raw.z & 0xffffu); xv[5] = b2f(raw.z >> 16);
  xv[6] = b2f(raw.w & 0xffffu); xv[7] = b2f(raw.w >> 16);
  bool nR = node < Nd;
  float v[8];
#pragma unroll
  for (int h = 0; h < 4; ++h) {
    const float* wp = wlr + h * 512 + lane * 8;
    float4 w0 = *reinterpret_cast<const float4*>(wp);
    float4 w1 = *reinterpret_cast<const float4*>(wp + 4);
    v[h] = xv[0]*w0.x + xv[1]*w0.y + xv[2]*w0.z + xv[3]*w0.w +
           xv[4]*w1.x + xv[5]*w1.y + xv[6]*w1.z + xv[7]*w1.w;
    v[4 + h] = 0.f;
    if (nR) {
      const float* wq = wlr + 2048 + h * 512 + lane * 8;
      float4 u0 = *reinterpret_cast<const float4*>(wq);
      float4 u1 = *reinterpret_cast<const float4*>(wq + 4);
      v[4 + h] = xv[0]*u0.x + xv[1]*u0.y + xv[2]*u0.z + xv[3]*u0.w +
                 xv[4]*u1.x + xv[5]*u1.y + xv[6]*u1.z + xv[7]*u1.w;
    }
  }
  reduce8_store(v, lane, node, Nd, ell, err);
}

// fused per-dst softmax + weighted bf16 feature gather (block = one dst node).
template <int FIN>
__global__ __launch_bounds__(FIN / 4) void k_gather_fused(
    const unsigned short* __restrict__ Hs, const float* __restrict__ ell,
    const float* __restrict__ err, const int* __restrict__ rowptr,
    const int* __restrict__ colv, unsigned short* __restrict__ Z) {
  constexpr int TB = FIN / 4;
  constexpr int NW = TB / 64;
  constexpr int CAP = 256;
  int n = blockIdx.x, t = threadIdx.x;
  int beg = rowptr[n], cnt = rowptr[n + 1] - beg;
  float4 er4 = *reinterpret_cast<const float4*>(err + (size_t)n * 4);
  __shared__ float4 esm[CAP];
  __shared__ int csm[CAP];
  __shared__ float4 wred[NW > 1 ? NW : 1];
  float m0 = -INFINITY, m1 = -INFINITY, m2 = -INFINITY, m3 = -INFINITY;
  for (int i = t; i < cnt; i += TB) {
    int c = colv[beg + i];
    float4 el4 = *reinterpret_cast<const float4*>(ell + (size_t)c * 4);
    float4 e4;
    e4.x = lrelu(el4.x + er4.x); e4.y = lrelu(el4.y + er4.y);
    e4.z = lrelu(el4.z + er4.z); e4.w = lrelu(el4.w + er4.w);
    if (i < CAP) { csm[i] = c; esm[i] = e4; }
    m0 = fmaxf(m0, e4.x); m1 = fmaxf(m1, e4.y);
    m2 = fmaxf(m2, e4.z); m3 = fmaxf(m3, e4.w);
  }
  for (int off = 32; off > 0; off >>= 1) {
    m0 = fmaxf(m0, __shfl_xor(m0, off));
    m1 = fmaxf(m1, __shfl_xor(m1, off));
    m2 = fmaxf(m2, __shfl_xor(m2, off));
    m3 = fmaxf(m3, __shfl_xor(m3, off));
  }
  if constexpr (NW > 1) {
    if ((t & 63) == 0) wred[t >> 6] = make_float4(m0, m1, m2, m3);
  }
  __syncthreads();  // esm/csm (+wred) visible
  if constexpr (NW > 1) {
    float4 wa = wred[0], wb = wred[1];
    m0 = fmaxf(wa.x, wb.x); m1 = fmaxf(wa.y, wb.y);
    m2 = fmaxf(wa.z, wb.z); m3 = fmaxf(wa.w, wb.w);
  }
  float s0 = 0.f, s1 = 0.f, s2 = 0.f, s3 = 0.f;
  float acc[4][4] = {};

#define GAT_ACC(e4, xr)                                                        \
  {                                                                            \
    float w0 = __expf(e4.x - m0), w1 = __expf(e4.y - m1);                      \
    float w2 = __expf(e4.z - m2), w3 = __expf(e4.w - m3);                      \
    s0 += w0; s1 += w1; s2 += w2; s3 += w3;                                    \
    float x0 = b2f(xr.x), x1 = b2f(xr.y), x2 = b2f(xr.z), x3 = b2f(xr.w);      \
    acc[0][0] = fmaf(w0, x0, acc[0][0]); acc[0][1] = fmaf(w0, x1, acc[0][1]);  \
    acc[0][2] = fmaf(w0, x2, acc[0][2]); acc[0][3] = fmaf(w0, x3, acc[0][3]);  \
    acc[1][0] = fmaf(w1, x0, acc[1][0]); acc[1][1] = fmaf(w1, x1, acc[1][1]);  \
    acc[1][2] = fmaf(w1, x2, acc[1][2]); acc[1][3] = fmaf(w1, x3, acc[1][3]);  \
    acc[2][0] = fmaf(w2, x0, acc[2][0]); acc[2][1] = fmaf(w2, x1, acc[2][1]);  \
    acc[2][2] = fmaf(w2, x2, acc[2][2]); acc[2][3] = fmaf(w2, x3, acc[2][3]);  \
    acc[3][0] = fmaf(w3, x0, acc[3][0]); acc[3][1] = fmaf(w3, x1, acc[3][1]);  \
    acc[3][2] = fmaf(w3, x2, acc[3][2]); acc[3][3] = fmaf(w3, x3, acc[3][3]);  \
  }

  if (cnt <= CAP) {
    int j = 0;
    for (; j + 2 <= cnt; j += 2) {
      float4 ea = esm[j], eb = esm[j + 1];
      int ca = csm[j], cb = csm[j + 1];
      ushort4 xa = *reinterpret_cast<const ushort4*>(Hs + (size_t)ca * FIN + t * 4);
      ushort4 xb = *reinterpret_cast<const ushort4*>(Hs + (size_t)cb * FIN + t * 4);
      GAT_ACC(ea, xa);
      GAT_ACC(eb, xb);
    }
    if (j < cnt) {
      float4 ea = esm[j];
      ushort4 xa = *reinterpret_cast<const ushort4*>(Hs + (size_t)csm[j] * FIN + t * 4);
      GAT_ACC(ea, xa);
    }
  } else {
    for (int j = 0; j < cnt; ++j) {
      int c = colv[beg + j];
      float4 el4 = *reinterpret_cast<const float4*>(ell + (size_t)c * 4);
      float4 e4;
      e4.x = lrelu(el4.x + er4.x); e4.y = lrelu(el4.y + er4.y);
      e4.z = lrelu(el4.z + er4.z); e4.w = lrelu(el4.w + er4.w);
      ushort4 xa = *reinterpret_cast<const ushort4*>(Hs + (size_t)c * FIN + t * 4);
      GAT_ACC(e4, xa);
    }
  }
#undef GAT_ACC
  float inv[4];
  inv[0] = 1.f / fmaxf(s0, 1e-9f); inv[1] = 1.f / fmaxf(s1, 1e-9f);
  inv[2] = 1.f / fmaxf(s2, 1e-9f); inv[3] = 1.f / fmaxf(s3, 1e-9f);
#pragma unroll
  for (int h = 0; h < 4; ++h) {
    ushort4 o;
    o.x = f2b(acc[h][0] * inv[h]); o.y = f2b(acc[h][1] * inv[h]);
    o.z = f2b(acc[h][2] * inv[h]); o.w = f2b(acc[h][3] * inv[h]);
    *reinterpret_cast<ushort4*>(Z + (size_t)n * 4 * FIN + h * FIN + t * 4) = o;
  }
}

// bf16 MFMA GEMM, per-head: out[m, h*N+n] = (Z_h @ W_h^T)[m,n] + bias  (opt ELU)
// 128xBN tile, BK=64, 256 thr (4 waves), global_load_lds staging, XOR swizzle.
template <int BN, bool ACT, bool OUTBF>
__global__ __launch_bounds__(256) void k_gemm_mfma(
    const unsigned short* __restrict__ Zb, const unsigned short* __restrict__ Wb,
    const float* __restrict__ bias, void* __restrict__ outv,
    int M, int N, int K) {
  constexpr int FN = BN / 16;
  constexpr int AI = 4;        // A gload instrs per thread (16 chunks / 4 waves)
  constexpr int BI = BN / 32;  // B gload instrs per thread
  int h = blockIdx.z;
  __shared__ unsigned short As[128 * 64];  // linear; 16KB
  __shared__ unsigned short Bs[BN * 64];
  const int tid = threadIdx.x;
  const int w = tid >> 6, lane = tid & 63;
  const int bm = blockIdx.x * 128, bn = blockIdx.y * BN;
  const int lda = 4 * K;
  const unsigned short* Ag = Zb + (size_t)h * K;
  const unsigned short* Bg = Wb + (size_t)h * N * K;
  const int lrow = lane >> 3;           // row within 8-row chunk
  const int gseg = (lane & 7) ^ lrow;   // swizzled source 16B-seg (involution)
  f32x4 acc[2][FN];
#pragma unroll
  for (int i = 0; i < 2; ++i)
#pragma unroll
    for (int j = 0; j < FN; ++j) acc[i][j] = (f32x4){0.f, 0.f, 0.f, 0.f};

  for (int k0 = 0; k0 < K; k0 += 64) {
    __syncthreads();  // prev iter's ds_reads done before DMA overwrite
#pragma unroll
    for (int i = 0; i < AI; ++i) {
      int ch = w * AI + i;            // 0..15
      int row = ch * 8 + lrow;        // 0..127
      int gm = bm + row; gm = gm < M ? gm : M - 1;
      gload16(Ag + (size_t)gm * lda + k0 + gseg * 8, As + ch * 512);
    }
#pragma unroll
    for (int i = 0; i < BI; ++i) {
      int ch = w * BI + i;
      int row = ch * 8 + lrow;        // 0..BN-1
      int gn = bn + row; gn = gn < N ? gn : N - 1;
      gload16(Bg + (size_t)gn * K + k0 + gseg * 8, Bs + ch * 512);
    }
    __syncthreads();  // compiler drains vmcnt(0) before barrier
    const int ra = w * 32 + (lane & 15);
#pragma unroll
    for (int ks = 0; ks < 2; ++ks) {
      int cs = ((((ks << 2) + (lane >> 4)) ^ (lane & 7)) << 3);  // swizzled k-offset (shorts)
      bf8_t a0 = *reinterpret_cast<const bf8_t*>(As + ra * 64 + cs);
      bf8_t a1 = *reinterpret_cast<const bf8_t*>(As + (ra + 16) * 64 + cs);
#pragma unroll
      for (int fn = 0; fn < FN; ++fn) {
        bf8_t bf = *reinterpret_cast<const bf8_t*>(Bs + (fn * 16 + (lane & 15)) * 64 + cs);
        acc[0][fn] = __builtin_amdgcn_mfma_f32_16x16x32_bf16(a0, bf, acc[0][fn], 0, 0, 0);
        acc[1][fn] = __builtin_amdgcn_mfma_f32_16x16x32_bf16(a1, bf, acc[1][fn], 0, 0, 0);
      }
    }
  }
  int ldo = 4 * N;
#pragma unroll
  for (int fm = 0; fm < 2; ++fm) {
#pragma unroll
    for (int fn = 0; fn < FN; ++fn) {
      int colb = bn + fn * 16 + (lane & 15);
      if (colb >= N) continue;
      float bv = bias[h * N + colb];
#pragma unroll
      for (int j = 0; j < 4; ++j) {
        int rowb = bm + w * 32 + fm * 16 + (lane >> 4) * 4 + j;
        if (rowb >= M) continue;
        float v = acc[fm][fn][j] + bv;
        if (ACT) v = v > 0.f ? v : (__expf(v) - 1.f);
        size_t off = (size_t)rowb * ldo + (size_t)h * N + colb;
        if (OUTBF) ((unsigned short*)outv)[off] = f2b(v);
        else ((float*)outv)[off] = v;
      }
    }
  }
}

// mean over 4 heads (C=47) + log_softmax; one wave per node
__global__ __launch_bounds__(256) void k_mean_lsm(const float* __restrict__ rst2,
                                                  float* __restrict__ out, int Nd) {
  int node = blockIdx.x * 4 + (threadIdx.x >> 6);
  int lane = threadIdx.x & 63;
  if (node >= Nd) return;
  const float* r = rst2 + (size_t)node * 188;
  float vv = 0.f;
  if (lane < 47)
    vv = 0.25f * (r[lane] + r[47 + lane] + r[94 + lane] + r[141 + lane]);
  float m = (lane < 47) ? vv : -INFINITY;
  for (int off = 32; off > 0; off >>= 1) m = fmaxf(m, __shfl_xor(m, off));
  float ex = (lane < 47) ? __expf(vv - m) : 0.f;
  float ss = ex;
  for (int off = 32; off > 0; off >>= 1) ss += __shfl_xor(ss, off);
  if (lane < 47) out[(size_t)node * 47 + lane] = vv - m - logf(ss);
}

extern "C" void kernel_launch(void* const* d_in, const int* in_sizes, int n_in,
                              void* d_out, int out_size, void* d_ws, size_t ws_size,
                              hipStream_t stream) {
  (void)in_sizes; (void)n_in; (void)out_size; (void)ws_size;
  const float* x = (const float*)d_in[0];
  const int* srcs[3] = {(const int*)d_in[1], (const int*)d_in[3], (const int*)d_in[5]};
  const int* dsts[3] = {(const int*)d_in[2], (const int*)d_in[4], (const int*)d_in[6]};
  const float* Wsrc[3] = {(const float*)d_in[7], (const float*)d_in[12], (const float*)d_in[17]};
  const float* Wdst[3] = {(const float*)d_in[8], (const float*)d_in[13], (const float*)d_in[18]};
  const float* al[3]   = {(const float*)d_in[9], (const float*)d_in[14], (const float*)d_in[19]};
  const float* ar[3]   = {(const float*)d_in[10], (const float*)d_in[15], (const float*)d_in[20]};
  const float* bb[3]   = {(const float*)d_in[11], (const float*)d_in[16], (const float*)d_in[21]};

  char* p = (char*)d_ws;
  auto alloc = [&](size_t bytes) -> void* {
    void* r = (void*)p;
    p += (bytes + 255) & ~(size_t)255;
    return r;
  };
  unsigned short* xbf = (unsigned short*)alloc((size_t)150000 * 256 * 2);
  unsigned short* zbf = (unsigned short*)alloc((size_t)25000 * 1024 * 2);
  unsigned short* h1  = (unsigned short*)alloc((size_t)25000 * 512 * 2);
  unsigned short* h2  = (unsigned short*)alloc((size_t)6000 * 512 * 2);
  float* rst2   = (float*)alloc((size_t)1024 * 188 * 4);
  unsigned short* Wb0 = (unsigned short*)alloc((size_t)512 * 256 * 2);
  unsigned short* Wb1 = (unsigned short*)alloc((size_t)512 * 512 * 2);
  unsigned short* Wb2 = (unsigned short*)alloc((size_t)188 * 512 * 2);
  float* ell    = (float*)alloc((size_t)150000 * 4 * 4);
  float* err    = (float*)alloc((size_t)25000 * 4 * 4);
  int* cntAll   = (int*)alloc((size_t)(25000 + 6000 + 1024) * 4);
  int* rp0      = (int*)alloc((size_t)25001 * 4);
  int* rp1      = (int*)alloc((size_t)6001 * 4);
  int* rp2      = (int*)alloc((size_t)1025 * 4);
  int* r_all    = (int*)alloc((size_t)ETOT * 4);
  int* cv0      = (int*)alloc((size_t)E0 * 4);
  int* cv1      = (int*)alloc((size_t)E1 * 4);
  int* cv2      = (int*)alloc((size_t)E2 * 4);
  float* wlr0   = (float*)alloc((size_t)8 * 256 * 4);
  float* wlr1   = (float*)alloc((size_t)8 * 512 * 4);
  float* wlr2   = (float*)alloc((size_t)8 * 512 * 4);

  int* cnt0 = cntAll, *cnt1 = cntAll + 25000, *cnt2 = cntAll + 31000;

  // ---- one-shot prologue: CSR + weight prep
  hipMemsetAsync(cntAll, 0, (size_t)(25000 + 6000 + 1024) * 4, stream);
  k_count_all<<<(ETOT + 255) / 256, 256, 0, stream>>>(
      dsts[0], dsts[1], dsts[2], cnt0, cnt1, cnt2, r_all);
  k_scan3<<<3, 1024, 0, stream>>>(cnt0, rp0, 25000, cnt1, rp1, 6000, cnt2, rp2, 1024);
  k_scatter_all<<<(ETOT + 255) / 256, 256, 0, stream>>>(
      srcs[0], dsts[0], rp0, cv0, srcs[1], dsts[1], rp1, cv1,
      srcs[2], dsts[2], rp2, cv2, r_all);
  k_build_wlr_all<<<(10240 + 255) / 256, 256, 0, stream>>>(
      Wsrc[0], Wdst[0], al[0], ar[0], Wsrc[1], Wdst[1], al[1], ar[1],
      Wsrc[2], Wdst[2], al[2], ar[2], wlr0, wlr1, wlr2);
  k_cvt_all<<<512, 256, 0, stream>>>(Wsrc[0], Wsrc[1], Wsrc[2], Wb0, Wb1, Wb2);

  const unsigned short* Hbf[3] = {xbf, h1, h2};
  const unsigned short* Wbf[3] = {Wb0, Wb1, Wb2};
  const float* wlrs[3] = {wlr0, wlr1, wlr2};
  const int* rps[3] = {rp0, rp1, rp2};
  const int* cvs[3] = {cv0, cv1, cv2};

  for (int l = 0; l < 3; ++l) {
    int Ns = L_NS[l], Nd = L_ND[l], Fin = L_FIN[l], Fout = L_FOUT[l];
    if (l == 0)
      k_dot_cvt<<<(Ns + 3) / 4, 256, 0, stream>>>(x, wlrs[l], xbf, ell, err, Ns, Nd);
    else
      k_dot_bf<<<(Ns + 3) / 4, 256, 0, stream>>>(Hbf[l], wlrs[l], ell, err, Ns, Nd);
    if (Fin == 256)
      k_gather_fused<256><<<Nd, 64, 0, stream>>>(Hbf[l], ell, err, rps[l], cvs[l], zbf);
    else
      k_gather_fused<512><<<Nd, 128, 0, stream>>>(Hbf[l], ell, err, rps[l], cvs[l], zbf);
    dim3 g((Nd + 127) / 128, 1, 4);
    if (l == 0)
      k_gemm_mfma<128, true, true><<<g, 256, 0, stream>>>(zbf, Wbf[l], bb[l], h1, Nd, Fout, Fin);
    else if (l == 1)
      k_gemm_mfma<128, true, true><<<g, 256, 0, stream>>>(zbf, Wbf[l], bb[l], h2, Nd, Fout, Fin);
    else
      k_gemm_mfma<64, false, false><<<g, 256, 0, stream>>>(zbf, Wbf[l], bb[l], rst2, Nd, Fout, Fin);
  }
  k_mean_lsm<<<(1024 + 3) / 4, 256, 0, stream>>>(rst2, (float*)d_out, 1024);
}